// Round 1
// baseline (2870.563 us; speedup 1.0000x reference)
//
#include <hip/hip_runtime.h>
#include <math.h>

#define D 25

// ---------------- degree: deg[i] += 1 for each edge with dst==i ----------------
__global__ void deg_kernel(const int* __restrict__ dst, float* __restrict__ deg, int E) {
    int e = blockIdx.x * blockDim.x + threadIdx.x;
    if (e < E) atomicAdd(&deg[dst[e]], 1.0f);
}

// ------------- layer1: hs = dinv * (emb[x] @ W1); A=hs, B=hs (self-loop init) -------------
__global__ __launch_bounds__(256) void embed_gemm1(
        const int* __restrict__ x, const float* __restrict__ emb,
        const float* __restrict__ W1, const float* __restrict__ deg,
        float* __restrict__ A, float* __restrict__ B, int N) {
    __shared__ float sW[D * D];
    for (int j = threadIdx.x; j < D * D; j += blockDim.x) sW[j] = W1[j];
    __syncthreads();
    int i = blockIdx.x * blockDim.x + threadIdx.x;
    if (i >= N) return;
    const float* er = emb + (size_t)x[i] * D;
    float t[D];
#pragma unroll
    for (int k = 0; k < D; ++k) t[k] = er[k];
    float dinv = rsqrtf(deg[i] + 1.0f);
#pragma unroll
    for (int d = 0; d < D; ++d) {
        float acc = 0.0f;
#pragma unroll
        for (int k = 0; k < D; ++k) acc = fmaf(t[k], sW[k * D + d], acc);
        float v = dinv * acc;
        A[i * D + d] = v;
        B[i * D + d] = v;
    }
}

// ---------------- scatter: B[dst] += A[src], 32 lanes per edge (25 active) ----------------
__global__ void scatter_kernel(const int* __restrict__ src, const int* __restrict__ dst,
                               const float* __restrict__ A, float* __restrict__ B, int E) {
    int idx = blockIdx.x * blockDim.x + threadIdx.x;
    int e = idx >> 5;
    int lane = idx & 31;
    if (e >= E || lane >= D) return;
    int s = src[e];
    int d = dst[e];
    atomicAdd(&B[d * D + lane], A[s * D + lane]);
}

// ------- finish: Aout = dinv*B + bias (pre-BN activation); accumulate BN stats -------
__global__ __launch_bounds__(256) void finish_stats(
        const float* __restrict__ Bagg, const float* __restrict__ deg,
        const float* __restrict__ bias, float* __restrict__ Aout,
        float* __restrict__ sum, float* __restrict__ sq, int N) {
    int i = blockIdx.x * blockDim.x + threadIdx.x;
    bool act = (i < N);
    float dinv = act ? rsqrtf(deg[i] + 1.0f) : 0.0f;
    float lv[D];
#pragma unroll
    for (int d = 0; d < D; ++d) {
        float v = act ? fmaf(dinv, Bagg[i * D + d], bias[d]) : 0.0f;
        lv[d] = v;
        if (act) Aout[i * D + d] = v;
    }
    int lane = threadIdx.x & 63;
#pragma unroll
    for (int d = 0; d < D; ++d) {
        float s = lv[d];
        float q = lv[d] * lv[d];
        for (int off = 32; off > 0; off >>= 1) {
            s += __shfl_down(s, off, 64);
            q += __shfl_down(q, off, 64);
        }
        if (lane == 0) {
            atomicAdd(&sum[d], s);
            atomicAdd(&sq[d], q);
        }
    }
}

// ---------------- mu / rstd from sums ----------------
__global__ void musig_kernel(const float* __restrict__ sum, const float* __restrict__ sq,
                             float* __restrict__ mu, float* __restrict__ rstd, float invN) {
    int d = threadIdx.x;
    if (d < D) {
        float m = sum[d] * invN;
        float v = fmaxf(sq[d] * invN - m * m, 0.0f);
        mu[d] = m;
        rstd[d] = rsqrtf(v + 1e-5f);
    }
}

// ------- layer2: t = relu(bn(A)); hs2 = dinv*(t@W2); A=hs2, B=hs2 -------
__global__ __launch_bounds__(256) void bn_gemm(
        const float* __restrict__ mu, const float* __restrict__ rstd,
        const float* __restrict__ g, const float* __restrict__ be,
        const float* __restrict__ W, const float* __restrict__ deg,
        float* __restrict__ A, float* __restrict__ B, int N) {
    __shared__ float sW[D * D];
    __shared__ float sScale[D], sShift[D];
    for (int j = threadIdx.x; j < D * D; j += blockDim.x) sW[j] = W[j];
    if (threadIdx.x < D) {
        float sc = rstd[threadIdx.x] * g[threadIdx.x];
        sScale[threadIdx.x] = sc;
        sShift[threadIdx.x] = be[threadIdx.x] - mu[threadIdx.x] * sc;
    }
    __syncthreads();
    int i = blockIdx.x * blockDim.x + threadIdx.x;
    if (i >= N) return;
    float t[D];
#pragma unroll
    for (int d = 0; d < D; ++d)
        t[d] = fmaxf(0.0f, fmaf(A[i * D + d], sScale[d], sShift[d]));
    float dinv = rsqrtf(deg[i] + 1.0f);
#pragma unroll
    for (int d = 0; d < D; ++d) {
        float acc = 0.0f;
#pragma unroll
        for (int k = 0; k < D; ++k) acc = fmaf(t[k], sW[k * D + d], acc);
        float v = dinv * acc;
        A[i * D + d] = v;
        B[i * D + d] = v;
    }
}

// ------- head: t = relu(bn(A)); m = relu(t@Wm1+bm1); out = sigmoid(m@Wm2+bm2) -------
__global__ __launch_bounds__(256) void final_kernel(
        const float* __restrict__ A,
        const float* __restrict__ mu, const float* __restrict__ rstd,
        const float* __restrict__ g, const float* __restrict__ be,
        const float* __restrict__ Wm1, const float* __restrict__ bm1,
        const float* __restrict__ Wm2, const float* __restrict__ bm2,
        float* __restrict__ out, int N) {
    __shared__ float sW1[D * 12];
    __shared__ float sb1[12], sW2[12];
    __shared__ float sScale[D], sShift[D];
    __shared__ float sb2;
    for (int j = threadIdx.x; j < D * 12; j += blockDim.x) sW1[j] = Wm1[j];
    if (threadIdx.x < 12) {
        sb1[threadIdx.x] = bm1[threadIdx.x];
        sW2[threadIdx.x] = Wm2[threadIdx.x];
    }
    if (threadIdx.x < D) {
        float sc = rstd[threadIdx.x] * g[threadIdx.x];
        sScale[threadIdx.x] = sc;
        sShift[threadIdx.x] = be[threadIdx.x] - mu[threadIdx.x] * sc;
    }
    if (threadIdx.x == 0) sb2 = bm2[0];
    __syncthreads();
    int i = blockIdx.x * blockDim.x + threadIdx.x;
    if (i >= N) return;
    float t[D];
#pragma unroll
    for (int d = 0; d < D; ++d)
        t[d] = fmaxf(0.0f, fmaf(A[i * D + d], sScale[d], sShift[d]));
    float z = sb2;
#pragma unroll
    for (int j = 0; j < 12; ++j) {
        float m = sb1[j];
#pragma unroll
        for (int k = 0; k < D; ++k) m = fmaf(t[k], sW1[k * 12 + j], m);
        m = fmaxf(0.0f, m);
        z = fmaf(m, sW2[j], z);
    }
    out[i] = 1.0f / (1.0f + expf(-z));
}

extern "C" void kernel_launch(void* const* d_in, const int* in_sizes, int n_in,
                              void* d_out, int out_size, void* d_ws, size_t ws_size,
                              hipStream_t stream) {
    const int*   x    = (const int*)d_in[0];
    const int*   ei   = (const int*)d_in[1];
    const float* emb  = (const float*)d_in[2];
    const float* W1   = (const float*)d_in[3];
    const float* b1   = (const float*)d_in[4];
    const float* g1   = (const float*)d_in[5];
    const float* be1  = (const float*)d_in[6];
    const float* W2   = (const float*)d_in[7];
    const float* b2   = (const float*)d_in[8];
    const float* g2   = (const float*)d_in[9];
    const float* be2  = (const float*)d_in[10];
    const float* Wm1  = (const float*)d_in[11];
    const float* bm1  = (const float*)d_in[12];
    const float* Wm2  = (const float*)d_in[13];
    const float* bm2  = (const float*)d_in[14];
    float* out = (float*)d_out;

    int N = in_sizes[0];
    int E = in_sizes[1] / 2;
    const int* src = ei;
    const int* dst = ei + E;

    float* ws    = (float*)d_ws;
    float* deg   = ws;                       // N
    float* A     = ws + N;                   // N*D
    float* B     = A + (size_t)N * D;        // N*D
    float* stats = B + (size_t)N * D;        // 200
    float* sum1 = stats;        float* sq1 = stats + 25;
    float* sum2 = stats + 50;   float* sq2 = stats + 75;
    float* mu1  = stats + 100;  float* rs1 = stats + 125;
    float* mu2  = stats + 150;  float* rs2 = stats + 175;

    hipMemsetAsync(deg, 0, (size_t)N * sizeof(float), stream);
    hipMemsetAsync(stats, 0, 100 * sizeof(float), stream);

    int nbN = (N + 255) / 256;
    int nbE = (E + 255) / 256;
    long scThreads = (long)E * 32;
    int nbS = (int)((scThreads + 255) / 256);

    deg_kernel<<<nbE, 256, 0, stream>>>(dst, deg, E);
    embed_gemm1<<<nbN, 256, 0, stream>>>(x, emb, W1, deg, A, B, N);
    scatter_kernel<<<nbS, 256, 0, stream>>>(src, dst, A, B, E);
    finish_stats<<<nbN, 256, 0, stream>>>(B, deg, b1, A, sum1, sq1, N);
    musig_kernel<<<1, 64, 0, stream>>>(sum1, sq1, mu1, rs1, 1.0f / (float)N);
    bn_gemm<<<nbN, 256, 0, stream>>>(mu1, rs1, g1, be1, W2, deg, A, B, N);
    scatter_kernel<<<nbS, 256, 0, stream>>>(src, dst, A, B, E);
    finish_stats<<<nbN, 256, 0, stream>>>(B, deg, b2, A, sum2, sq2, N);
    musig_kernel<<<1, 64, 0, stream>>>(sum2, sq2, mu2, rs2, 1.0f / (float)N);
    final_kernel<<<nbN, 256, 0, stream>>>(A, mu2, rs2, g2, be2, Wm1, bm1, Wm2, bm2, out, N);
}

// Round 2
// 1169.826 us; speedup vs baseline: 2.4538x; 2.4538x over previous
//
#include <hip/hip_runtime.h>
#include <math.h>

#define D 25
#define STATS_BLOCKS 512

// ---------------- degree: deg[i] += 1 for each edge with dst==i ----------------
__global__ void deg_kernel(const int* __restrict__ dst, float* __restrict__ deg, int E) {
    int e = blockIdx.x * blockDim.x + threadIdx.x;
    if (e < E) atomicAdd(&deg[dst[e]], 1.0f);
}

// ------------- layer1: hs = dinv * (emb[x] @ W1); A=hs, B=hs (self-loop init) -------------
__global__ __launch_bounds__(256) void embed_gemm1(
        const int* __restrict__ x, const float* __restrict__ emb,
        const float* __restrict__ W1, const float* __restrict__ deg,
        float* __restrict__ A, float* __restrict__ B, int N) {
    __shared__ float sW[D * D];
    for (int j = threadIdx.x; j < D * D; j += blockDim.x) sW[j] = W1[j];
    __syncthreads();
    int i = blockIdx.x * blockDim.x + threadIdx.x;
    if (i >= N) return;
    const float* er = emb + (size_t)x[i] * D;
    float t[D];
#pragma unroll
    for (int k = 0; k < D; ++k) t[k] = er[k];
    float dinv = rsqrtf(deg[i] + 1.0f);
#pragma unroll
    for (int d = 0; d < D; ++d) {
        float acc = 0.0f;
#pragma unroll
        for (int k = 0; k < D; ++k) acc = fmaf(t[k], sW[k * D + d], acc);
        float v = dinv * acc;
        A[i * D + d] = v;
        B[i * D + d] = v;
    }
}

// ---------------- scatter: B[dst] += A[src], 32 lanes per edge (25 active) ----------------
__global__ void scatter_kernel(const int* __restrict__ src, const int* __restrict__ dst,
                               const float* __restrict__ A, float* __restrict__ B, int E) {
    int idx = blockIdx.x * blockDim.x + threadIdx.x;
    int e = idx >> 5;
    int lane = idx & 31;
    if (e >= E || lane >= D) return;
    int s = src[e];
    int d = dst[e];
    atomicAdd(&B[d * D + lane], A[s * D + lane]);
}

// ------- finish: Aout = dinv*B + bias (pre-BN activation); 3-level stats reduction -------
// stats layout at `st`: st[0..24] = sum, st[25..49] = sumsq
__global__ __launch_bounds__(256) void finish_stats(
        const float* __restrict__ Bagg, const float* __restrict__ deg,
        const float* __restrict__ bias, float* __restrict__ Aout,
        float* __restrict__ st, int N) {
    float ls[D], lq[D];
#pragma unroll
    for (int d = 0; d < D; ++d) { ls[d] = 0.0f; lq[d] = 0.0f; }

    for (int i = blockIdx.x * blockDim.x + threadIdx.x; i < N;
         i += gridDim.x * blockDim.x) {
        float dinv = rsqrtf(deg[i] + 1.0f);
#pragma unroll
        for (int d = 0; d < D; ++d) {
            float v = fmaf(dinv, Bagg[i * D + d], bias[d]);
            Aout[i * D + d] = v;
            ls[d] += v;
            lq[d] += v * v;
        }
    }

    // wave-level shuffle reduction (64 lanes)
#pragma unroll
    for (int d = 0; d < D; ++d) {
        for (int off = 32; off > 0; off >>= 1) {
            ls[d] += __shfl_down(ls[d], off, 64);
            lq[d] += __shfl_down(lq[d], off, 64);
        }
    }

    // cross-wave via LDS (4 waves of 256-thread block)
    __shared__ float red[4][2 * D];
    int wave = threadIdx.x >> 6;
    int lane = threadIdx.x & 63;
    if (lane == 0) {
#pragma unroll
        for (int d = 0; d < D; ++d) {
            red[wave][d] = ls[d];
            red[wave][D + d] = lq[d];
        }
    }
    __syncthreads();
    if (threadIdx.x < 2 * D) {
        float t = red[0][threadIdx.x] + red[1][threadIdx.x] +
                  red[2][threadIdx.x] + red[3][threadIdx.x];
        atomicAdd(&st[threadIdx.x], t);   // one atomic per block per stat
    }
}

// ---------------- mu / rstd from sums ----------------
__global__ void musig_kernel(const float* __restrict__ sum, const float* __restrict__ sq,
                             float* __restrict__ mu, float* __restrict__ rstd, float invN) {
    int d = threadIdx.x;
    if (d < D) {
        float m = sum[d] * invN;
        float v = fmaxf(sq[d] * invN - m * m, 0.0f);
        mu[d] = m;
        rstd[d] = rsqrtf(v + 1e-5f);
    }
}

// ------- layer2: t = relu(bn(A)); hs2 = dinv*(t@W2); A=hs2, B=hs2 -------
__global__ __launch_bounds__(256) void bn_gemm(
        const float* __restrict__ mu, const float* __restrict__ rstd,
        const float* __restrict__ g, const float* __restrict__ be,
        const float* __restrict__ W, const float* __restrict__ deg,
        float* __restrict__ A, float* __restrict__ B, int N) {
    __shared__ float sW[D * D];
    __shared__ float sScale[D], sShift[D];
    for (int j = threadIdx.x; j < D * D; j += blockDim.x) sW[j] = W[j];
    if (threadIdx.x < D) {
        float sc = rstd[threadIdx.x] * g[threadIdx.x];
        sScale[threadIdx.x] = sc;
        sShift[threadIdx.x] = be[threadIdx.x] - mu[threadIdx.x] * sc;
    }
    __syncthreads();
    int i = blockIdx.x * blockDim.x + threadIdx.x;
    if (i >= N) return;
    float t[D];
#pragma unroll
    for (int d = 0; d < D; ++d)
        t[d] = fmaxf(0.0f, fmaf(A[i * D + d], sScale[d], sShift[d]));
    float dinv = rsqrtf(deg[i] + 1.0f);
#pragma unroll
    for (int d = 0; d < D; ++d) {
        float acc = 0.0f;
#pragma unroll
        for (int k = 0; k < D; ++k) acc = fmaf(t[k], sW[k * D + d], acc);
        float v = dinv * acc;
        A[i * D + d] = v;
        B[i * D + d] = v;
    }
}

// ------- head: t = relu(bn(A)); m = relu(t@Wm1+bm1); out = sigmoid(m@Wm2+bm2) -------
__global__ __launch_bounds__(256) void final_kernel(
        const float* __restrict__ A,
        const float* __restrict__ mu, const float* __restrict__ rstd,
        const float* __restrict__ g, const float* __restrict__ be,
        const float* __restrict__ Wm1, const float* __restrict__ bm1,
        const float* __restrict__ Wm2, const float* __restrict__ bm2,
        float* __restrict__ out, int N) {
    __shared__ float sW1[D * 12];
    __shared__ float sb1[12], sW2[12];
    __shared__ float sScale[D], sShift[D];
    __shared__ float sb2;
    for (int j = threadIdx.x; j < D * 12; j += blockDim.x) sW1[j] = Wm1[j];
    if (threadIdx.x < 12) {
        sb1[threadIdx.x] = bm1[threadIdx.x];
        sW2[threadIdx.x] = Wm2[threadIdx.x];
    }
    if (threadIdx.x < D) {
        float sc = rstd[threadIdx.x] * g[threadIdx.x];
        sScale[threadIdx.x] = sc;
        sShift[threadIdx.x] = be[threadIdx.x] - mu[threadIdx.x] * sc;
    }
    if (threadIdx.x == 0) sb2 = bm2[0];
    __syncthreads();
    int i = blockIdx.x * blockDim.x + threadIdx.x;
    if (i >= N) return;
    float t[D];
#pragma unroll
    for (int d = 0; d < D; ++d)
        t[d] = fmaxf(0.0f, fmaf(A[i * D + d], sScale[d], sShift[d]));
    float z = sb2;
#pragma unroll
    for (int j = 0; j < 12; ++j) {
        float m = sb1[j];
#pragma unroll
        for (int k = 0; k < D; ++k) m = fmaf(t[k], sW1[k * 12 + j], m);
        m = fmaxf(0.0f, m);
        z = fmaf(m, sW2[j], z);
    }
    out[i] = 1.0f / (1.0f + expf(-z));
}

extern "C" void kernel_launch(void* const* d_in, const int* in_sizes, int n_in,
                              void* d_out, int out_size, void* d_ws, size_t ws_size,
                              hipStream_t stream) {
    const int*   x    = (const int*)d_in[0];
    const int*   ei   = (const int*)d_in[1];
    const float* emb  = (const float*)d_in[2];
    const float* W1   = (const float*)d_in[3];
    const float* b1   = (const float*)d_in[4];
    const float* g1   = (const float*)d_in[5];
    const float* be1  = (const float*)d_in[6];
    const float* W2   = (const float*)d_in[7];
    const float* b2   = (const float*)d_in[8];
    const float* g2   = (const float*)d_in[9];
    const float* be2  = (const float*)d_in[10];
    const float* Wm1  = (const float*)d_in[11];
    const float* bm1  = (const float*)d_in[12];
    const float* Wm2  = (const float*)d_in[13];
    const float* bm2  = (const float*)d_in[14];
    float* out = (float*)d_out;

    int N = in_sizes[0];
    int E = in_sizes[1] / 2;
    const int* src = ei;
    const int* dst = ei + E;

    float* ws    = (float*)d_ws;
    float* deg   = ws;                       // N
    float* A     = ws + N;                   // N*D
    float* B     = A + (size_t)N * D;        // N*D
    float* stats = B + (size_t)N * D;        // 200
    float* st1  = stats;        // sum1[0..24], sq1[25..49]
    float* st2  = stats + 50;   // sum2[0..24], sq2[25..49]
    float* mu1  = stats + 100;  float* rs1 = stats + 125;
    float* mu2  = stats + 150;  float* rs2 = stats + 175;

    hipMemsetAsync(deg, 0, (size_t)N * sizeof(float), stream);
    hipMemsetAsync(stats, 0, 100 * sizeof(float), stream);

    int nbN = (N + 255) / 256;
    int nbE = (E + 255) / 256;
    long scThreads = (long)E * 32;
    int nbS = (int)((scThreads + 255) / 256);

    deg_kernel<<<nbE, 256, 0, stream>>>(dst, deg, E);
    embed_gemm1<<<nbN, 256, 0, stream>>>(x, emb, W1, deg, A, B, N);
    scatter_kernel<<<nbS, 256, 0, stream>>>(src, dst, A, B, E);
    finish_stats<<<STATS_BLOCKS, 256, 0, stream>>>(B, deg, b1, A, st1, N);
    musig_kernel<<<1, 64, 0, stream>>>(st1, st1 + 25, mu1, rs1, 1.0f / (float)N);
    bn_gemm<<<nbN, 256, 0, stream>>>(mu1, rs1, g1, be1, W2, deg, A, B, N);
    scatter_kernel<<<nbS, 256, 0, stream>>>(src, dst, A, B, E);
    finish_stats<<<STATS_BLOCKS, 256, 0, stream>>>(B, deg, b2, A, st2, N);
    musig_kernel<<<1, 64, 0, stream>>>(st2, st2 + 25, mu2, rs2, 1.0f / (float)N);
    final_kernel<<<nbN, 256, 0, stream>>>(A, mu2, rs2, g2, be2, Wm1, bm1, Wm2, bm2, out, N);
}

// Round 3
// 901.594 us; speedup vs baseline: 3.1839x; 1.2975x over previous
//
#include <hip/hip_runtime.h>
#include <math.h>

#define D 25
#define STATS_BLOCKS 512
#define SCAN_CHUNK 1024   // 256 threads x 4 elems

// ---------------- histogram: degi[i] += 1 for each edge with dst==i ----------------
__global__ void hist_kernel(const int* __restrict__ dst, int* __restrict__ degi, int E) {
    int e = blockIdx.x * blockDim.x + threadIdx.x;
    if (e < E) atomicAdd(&degi[dst[e]], 1);
}

// ---------------- scan step A: per-chunk sums ----------------
__global__ __launch_bounds__(256) void chunk_sum(const int* __restrict__ degi,
                                                 int* __restrict__ bsums, int N) {
    __shared__ int s[256];
    int base = blockIdx.x * SCAN_CHUNK + threadIdx.x * 4;
    int v = 0;
#pragma unroll
    for (int j = 0; j < 4; ++j) {
        int idx = base + j;
        if (idx < N) v += degi[idx];
    }
    s[threadIdx.x] = v;
    __syncthreads();
    for (int off = 128; off > 0; off >>= 1) {
        if (threadIdx.x < off) s[threadIdx.x] += s[threadIdx.x + off];
        __syncthreads();
    }
    if (threadIdx.x == 0) bsums[blockIdx.x] = s[0];
}

// ---------------- scan step B: exclusive scan of chunk sums (1 block, NB<=256) ----------------
__global__ void scan_bsums(int* __restrict__ bsums, int NB) {
    __shared__ int s[256];
    int t = threadIdx.x;
    s[t] = (t < NB) ? bsums[t] : 0;
    __syncthreads();
    for (int off = 1; off < 256; off <<= 1) {
        int x = (t >= off) ? s[t - off] : 0;
        __syncthreads();
        s[t] += x;
        __syncthreads();
    }
    if (t < NB) bsums[t] = (t > 0) ? s[t - 1] : 0;
}

// ---------------- scan step C: per-chunk exclusive scan + offset -> cursor (=row_start) ----------------
__global__ __launch_bounds__(256) void scan_chunks(const int* __restrict__ degi,
                                                   const int* __restrict__ bsums,
                                                   int* __restrict__ cursor, int N) {
    __shared__ int s[256];
    int t = threadIdx.x;
    int base = blockIdx.x * SCAN_CHUNK + t * 4;
    int v[4];
#pragma unroll
    for (int j = 0; j < 4; ++j) v[j] = (base + j < N) ? degi[base + j] : 0;
    int tot = v[0] + v[1] + v[2] + v[3];
    s[t] = tot;
    __syncthreads();
    for (int off = 1; off < 256; off <<= 1) {
        int x = (t >= off) ? s[t - off] : 0;
        __syncthreads();
        s[t] += x;
        __syncthreads();
    }
    int pre = bsums[blockIdx.x] + ((t > 0) ? s[t - 1] : 0);
#pragma unroll
    for (int j = 0; j < 4; ++j) {
        if (base + j < N) cursor[base + j] = pre;
        pre += v[j];
    }
}

// ---------------- fill: csr[cursor[dst]++] = src ----------------
__global__ void fill_csr(const int* __restrict__ src, const int* __restrict__ dst,
                         int* __restrict__ cursor, int* __restrict__ csr, int E) {
    int e = blockIdx.x * blockDim.x + threadIdx.x;
    if (e < E) {
        int p = atomicAdd(&cursor[dst[e]], 1);
        csr[p] = src[e];
    }
}

// ------------- layer1: P = dinv * (emb[x] @ W1); optional dup into Q (fallback self-init) -------------
__global__ __launch_bounds__(256) void embed_gemm1(
        const int* __restrict__ x, const float* __restrict__ emb,
        const float* __restrict__ W1, const int* __restrict__ degi,
        float* __restrict__ P, float* __restrict__ Qdup, int N) {
    __shared__ float sW[D * D];
    for (int j = threadIdx.x; j < D * D; j += blockDim.x) sW[j] = W1[j];
    __syncthreads();
    int i = blockIdx.x * blockDim.x + threadIdx.x;
    if (i >= N) return;
    const float* er = emb + (size_t)x[i] * D;
    float t[D];
#pragma unroll
    for (int k = 0; k < D; ++k) t[k] = er[k];
    float dinv = rsqrtf((float)degi[i] + 1.0f);
#pragma unroll
    for (int d = 0; d < D; ++d) {
        float acc = 0.0f;
#pragma unroll
        for (int k = 0; k < D; ++k) acc = fmaf(t[k], sW[k * D + d], acc);
        float v = dinv * acc;
        P[i * D + d] = v;
        if (Qdup) Qdup[i * D + d] = v;
    }
}

// ------- gather + finish: Q[i] = dinv_i * (P[i] + sum_{s in nbrs(i)} P[s]) + bias -------
// 32 lanes per node (25 active). cursor holds row_end after fill; start = end - deg.
__global__ __launch_bounds__(256) void gather_finish(
        const int* __restrict__ csr, const int* __restrict__ cursor,
        const int* __restrict__ degi, const float* __restrict__ P,
        const float* __restrict__ bias, float* __restrict__ Q, int N) {
    int idx = blockIdx.x * blockDim.x + threadIdx.x;
    int node = idx >> 5;
    int lane = idx & 31;
    if (node >= N) return;
    bool act = (lane < D);
    int end = cursor[node];
    int dg = degi[node];
    int start = end - dg;
    float acc = act ? P[node * D + lane] : 0.0f;   // self loop
    int k = start;
    while (k + 2 <= end) {
        int s0 = csr[k];
        int s1 = csr[k + 1];
        float v0 = act ? P[s0 * D + lane] : 0.0f;
        float v1 = act ? P[s1 * D + lane] : 0.0f;
        acc += v0 + v1;
        k += 2;
    }
    if (k < end) {
        int s0 = csr[k];
        acc += act ? P[s0 * D + lane] : 0.0f;
    }
    if (act) {
        float dinv = rsqrtf((float)dg + 1.0f);
        Q[node * D + lane] = fmaf(dinv, acc, bias[lane]);
    }
}

// ---------------- fallback scatter (atomics) ----------------
__global__ void scatter_kernel(const int* __restrict__ src, const int* __restrict__ dst,
                               const float* __restrict__ A, float* __restrict__ B, int E) {
    int idx = blockIdx.x * blockDim.x + threadIdx.x;
    int e = idx >> 5;
    int lane = idx & 31;
    if (e >= E || lane >= D) return;
    atomicAdd(&B[dst[e] * D + lane], A[src[e] * D + lane]);
}

// ---------------- fallback transform: Q = dinv*Q + bias, in place ----------------
__global__ __launch_bounds__(256) void transform_kernel(
        float* __restrict__ Q, const int* __restrict__ degi,
        const float* __restrict__ bias, int N) {
    int i = blockIdx.x * blockDim.x + threadIdx.x;
    if (i >= N) return;
    float dinv = rsqrtf((float)degi[i] + 1.0f);
#pragma unroll
    for (int d = 0; d < D; ++d)
        Q[i * D + d] = fmaf(dinv, Q[i * D + d], bias[d]);
}

// ---------------- stats over Q: st[0..24]=sum, st[25..49]=sumsq ----------------
__global__ __launch_bounds__(256) void stats_kernel(
        const float* __restrict__ Q, float* __restrict__ st, int N) {
    float ls[D], lq[D];
#pragma unroll
    for (int d = 0; d < D; ++d) { ls[d] = 0.0f; lq[d] = 0.0f; }
    for (int i = blockIdx.x * blockDim.x + threadIdx.x; i < N;
         i += gridDim.x * blockDim.x) {
#pragma unroll
        for (int d = 0; d < D; ++d) {
            float v = Q[i * D + d];
            ls[d] += v;
            lq[d] += v * v;
        }
    }
#pragma unroll
    for (int d = 0; d < D; ++d) {
        for (int off = 32; off > 0; off >>= 1) {
            ls[d] += __shfl_down(ls[d], off, 64);
            lq[d] += __shfl_down(lq[d], off, 64);
        }
    }
    __shared__ float red[4][2 * D];
    int wave = threadIdx.x >> 6;
    int lane = threadIdx.x & 63;
    if (lane == 0) {
#pragma unroll
        for (int d = 0; d < D; ++d) {
            red[wave][d] = ls[d];
            red[wave][D + d] = lq[d];
        }
    }
    __syncthreads();
    if (threadIdx.x < 2 * D) {
        float t = red[0][threadIdx.x] + red[1][threadIdx.x] +
                  red[2][threadIdx.x] + red[3][threadIdx.x];
        atomicAdd(&st[threadIdx.x], t);
    }
}

// ---------------- mu / rstd ----------------
__global__ void musig_kernel(const float* __restrict__ sum, const float* __restrict__ sq,
                             float* __restrict__ mu, float* __restrict__ rstd, float invN) {
    int d = threadIdx.x;
    if (d < D) {
        float m = sum[d] * invN;
        float v = fmaxf(sq[d] * invN - m * m, 0.0f);
        mu[d] = m;
        rstd[d] = rsqrtf(v + 1e-5f);
    }
}

// ------- layer2: t = relu(bn(Q)); P = dinv*(t@W2); optional dup into Qdup -------
__global__ __launch_bounds__(256) void bn_gemm(
        const float* __restrict__ Qin,
        const float* __restrict__ mu, const float* __restrict__ rstd,
        const float* __restrict__ g, const float* __restrict__ be,
        const float* __restrict__ W, const int* __restrict__ degi,
        float* __restrict__ P, float* __restrict__ Qdup, int N) {
    __shared__ float sW[D * D];
    __shared__ float sScale[D], sShift[D];
    for (int j = threadIdx.x; j < D * D; j += blockDim.x) sW[j] = W[j];
    if (threadIdx.x < D) {
        float sc = rstd[threadIdx.x] * g[threadIdx.x];
        sScale[threadIdx.x] = sc;
        sShift[threadIdx.x] = be[threadIdx.x] - mu[threadIdx.x] * sc;
    }
    __syncthreads();
    int i = blockIdx.x * blockDim.x + threadIdx.x;
    if (i >= N) return;
    float t[D];
#pragma unroll
    for (int d = 0; d < D; ++d)
        t[d] = fmaxf(0.0f, fmaf(Qin[i * D + d], sScale[d], sShift[d]));
    float dinv = rsqrtf((float)degi[i] + 1.0f);
#pragma unroll
    for (int d = 0; d < D; ++d) {
        float acc = 0.0f;
#pragma unroll
        for (int k = 0; k < D; ++k) acc = fmaf(t[k], sW[k * D + d], acc);
        float v = dinv * acc;
        P[i * D + d] = v;
        if (Qdup) Qdup[i * D + d] = v;
    }
}

// ------- head: t = relu(bn(Q)); m = relu(t@Wm1+bm1); out = sigmoid(m@Wm2+bm2) -------
__global__ __launch_bounds__(256) void final_kernel(
        const float* __restrict__ Q,
        const float* __restrict__ mu, const float* __restrict__ rstd,
        const float* __restrict__ g, const float* __restrict__ be,
        const float* __restrict__ Wm1, const float* __restrict__ bm1,
        const float* __restrict__ Wm2, const float* __restrict__ bm2,
        float* __restrict__ out, int N) {
    __shared__ float sW1[D * 12];
    __shared__ float sb1[12], sW2[12];
    __shared__ float sScale[D], sShift[D];
    __shared__ float sb2;
    for (int j = threadIdx.x; j < D * 12; j += blockDim.x) sW1[j] = Wm1[j];
    if (threadIdx.x < 12) {
        sb1[threadIdx.x] = bm1[threadIdx.x];
        sW2[threadIdx.x] = Wm2[threadIdx.x];
    }
    if (threadIdx.x < D) {
        float sc = rstd[threadIdx.x] * g[threadIdx.x];
        sScale[threadIdx.x] = sc;
        sShift[threadIdx.x] = be[threadIdx.x] - mu[threadIdx.x] * sc;
    }
    if (threadIdx.x == 0) sb2 = bm2[0];
    __syncthreads();
    int i = blockIdx.x * blockDim.x + threadIdx.x;
    if (i >= N) return;
    float t[D];
#pragma unroll
    for (int d = 0; d < D; ++d)
        t[d] = fmaxf(0.0f, fmaf(Q[i * D + d], sScale[d], sShift[d]));
    float z = sb2;
#pragma unroll
    for (int j = 0; j < 12; ++j) {
        float m = sb1[j];
#pragma unroll
        for (int k = 0; k < D; ++k) m = fmaf(t[k], sW1[k * 12 + j], m);
        m = fmaxf(0.0f, m);
        z = fmaf(m, sW2[j], z);
    }
    out[i] = 1.0f / (1.0f + expf(-z));
}

extern "C" void kernel_launch(void* const* d_in, const int* in_sizes, int n_in,
                              void* d_out, int out_size, void* d_ws, size_t ws_size,
                              hipStream_t stream) {
    const int*   x    = (const int*)d_in[0];
    const int*   ei   = (const int*)d_in[1];
    const float* emb  = (const float*)d_in[2];
    const float* W1   = (const float*)d_in[3];
    const float* b1   = (const float*)d_in[4];
    const float* g1   = (const float*)d_in[5];
    const float* be1  = (const float*)d_in[6];
    const float* W2   = (const float*)d_in[7];
    const float* b2   = (const float*)d_in[8];
    const float* g2   = (const float*)d_in[9];
    const float* be2  = (const float*)d_in[10];
    const float* Wm1  = (const float*)d_in[11];
    const float* bm1  = (const float*)d_in[12];
    const float* Wm2  = (const float*)d_in[13];
    const float* bm2  = (const float*)d_in[14];
    float* out = (float*)d_out;

    int N = in_sizes[0];
    int E = in_sizes[1] / 2;
    const int* src = ei;
    const int* dst = ei + E;

    size_t csrNeed = ((size_t)2 * N + E + 256 + (size_t)50 * N + 200) * 4;
    bool useCSR = (ws_size >= csrNeed);

    int nbN  = (N + 255) / 256;
    int nbE  = (E + 255) / 256;
    int nbG  = (int)(((long)N * 32 + 255) / 256);
    int nbS  = (int)(((long)E * 32 + 255) / 256);
    int NB   = (N + SCAN_CHUNK - 1) / SCAN_CHUNK;   // scan chunks (<=256 for N<=262144)

    if (useCSR) {
        int*   degi   = (int*)d_ws;                 // N
        int*   cursor = degi + N;                   // N
        int*   csr    = cursor + N;                 // E
        int*   bsums  = csr + E;                    // 256
        float* P      = (float*)(bsums + 256);      // N*D
        float* Q      = P + (size_t)N * D;          // N*D
        float* stats  = Q + (size_t)N * D;          // 200
        float* st1 = stats;       float* st2 = stats + 50;
        float* mu1 = stats + 100; float* rs1 = stats + 125;
        float* mu2 = stats + 150; float* rs2 = stats + 175;

        hipMemsetAsync(degi, 0, (size_t)N * sizeof(int), stream);
        hipMemsetAsync(stats, 0, 100 * sizeof(float), stream);

        hist_kernel<<<nbE, 256, 0, stream>>>(dst, degi, E);
        chunk_sum<<<NB, 256, 0, stream>>>(degi, bsums, N);
        scan_bsums<<<1, 256, 0, stream>>>(bsums, NB);
        scan_chunks<<<NB, 256, 0, stream>>>(degi, bsums, cursor, N);
        fill_csr<<<nbE, 256, 0, stream>>>(src, dst, cursor, csr, E);
        embed_gemm1<<<nbN, 256, 0, stream>>>(x, emb, W1, degi, P, nullptr, N);
        gather_finish<<<nbG, 256, 0, stream>>>(csr, cursor, degi, P, b1, Q, N);
        stats_kernel<<<STATS_BLOCKS, 256, 0, stream>>>(Q, st1, N);
        musig_kernel<<<1, 64, 0, stream>>>(st1, st1 + 25, mu1, rs1, 1.0f / (float)N);
        bn_gemm<<<nbN, 256, 0, stream>>>(Q, mu1, rs1, g1, be1, W2, degi, P, nullptr, N);
        gather_finish<<<nbG, 256, 0, stream>>>(csr, cursor, degi, P, b2, Q, N);
        stats_kernel<<<STATS_BLOCKS, 256, 0, stream>>>(Q, st2, N);
        musig_kernel<<<1, 64, 0, stream>>>(st2, st2 + 25, mu2, rs2, 1.0f / (float)N);
        final_kernel<<<nbN, 256, 0, stream>>>(Q, mu2, rs2, g2, be2, Wm1, bm1, Wm2, bm2, out, N);
    } else {
        // fallback: R2 atomic-scatter path
        int*   degi  = (int*)d_ws;                  // N
        float* P     = (float*)(degi + N);          // N*D
        float* Q     = P + (size_t)N * D;           // N*D
        float* stats = Q + (size_t)N * D;           // 200
        float* st1 = stats;       float* st2 = stats + 50;
        float* mu1 = stats + 100; float* rs1 = stats + 125;
        float* mu2 = stats + 150; float* rs2 = stats + 175;

        hipMemsetAsync(degi, 0, (size_t)N * sizeof(int), stream);
        hipMemsetAsync(stats, 0, 100 * sizeof(float), stream);

        hist_kernel<<<nbE, 256, 0, stream>>>(dst, degi, E);
        embed_gemm1<<<nbN, 256, 0, stream>>>(x, emb, W1, degi, P, Q, N);
        scatter_kernel<<<nbS, 256, 0, stream>>>(src, dst, P, Q, E);
        transform_kernel<<<nbN, 256, 0, stream>>>(Q, degi, b1, N);
        stats_kernel<<<STATS_BLOCKS, 256, 0, stream>>>(Q, st1, N);
        musig_kernel<<<1, 64, 0, stream>>>(st1, st1 + 25, mu1, rs1, 1.0f / (float)N);
        bn_gemm<<<nbN, 256, 0, stream>>>(Q, mu1, rs1, g1, be1, W2, degi, P, Q, N);
        scatter_kernel<<<nbS, 256, 0, stream>>>(src, dst, P, Q, E);
        transform_kernel<<<nbN, 256, 0, stream>>>(Q, degi, b2, N);
        stats_kernel<<<STATS_BLOCKS, 256, 0, stream>>>(Q, st2, N);
        musig_kernel<<<1, 64, 0, stream>>>(st2, st2 + 25, mu2, rs2, 1.0f / (float)N);
        final_kernel<<<nbN, 256, 0, stream>>>(Q, mu2, rs2, g2, be2, Wm1, bm1, Wm2, bm2, out, N);
    }
}

// Round 4
// 608.170 us; speedup vs baseline: 4.7200x; 1.4825x over previous
//
#include <hip/hip_runtime.h>
#include <math.h>

#define D 25
#define STATS_BLOCKS 512
#define NBK 256        // max buckets (1024 nodes each)
#define BIN_EPT 16     // edges per thread in bin_edges

// ---------------- bucket histogram: count[b] = #edges with dst>>10 == b ----------------
__global__ __launch_bounds__(256) void bucket_hist(const int* __restrict__ dst,
                                                   int* __restrict__ bucketCount, int E) {
    __shared__ int h[NBK];
    h[threadIdx.x] = 0;
    __syncthreads();
    for (int e = blockIdx.x * blockDim.x + threadIdx.x; e < E; e += gridDim.x * blockDim.x)
        atomicAdd(&h[dst[e] >> 10], 1);
    __syncthreads();
    int c = h[threadIdx.x];
    if (c) atomicAdd(&bucketCount[threadIdx.x], c);
}

// ---------------- exclusive scan of bucket counts (1 block, 256 threads) ----------------
__global__ void bucket_scan(const int* __restrict__ bucketCount,
                            int* __restrict__ bucketBase, int* __restrict__ bucketCursor) {
    __shared__ int s[NBK];
    int t = threadIdx.x;
    s[t] = bucketCount[t];
    __syncthreads();
    for (int off = 1; off < NBK; off <<= 1) {
        int x = (t >= off) ? s[t - off] : 0;
        __syncthreads();
        s[t] += x;
        __syncthreads();
    }
    int base = (t > 0) ? s[t - 1] : 0;
    bucketBase[t] = base;
    bucketCursor[t] = base;
}

// ------- binning: binned[] gets keys (src<<10 | dst&1023) grouped by bucket -------
__global__ __launch_bounds__(256) void bin_edges(const int* __restrict__ src,
                                                 const int* __restrict__ dst,
                                                 int* __restrict__ bucketCursor,
                                                 int* __restrict__ binned, int E) {
    __shared__ int hist[NBK], rank[NBK], basew[NBK];
    hist[threadIdx.x] = 0;
    rank[threadIdx.x] = 0;
    __syncthreads();
    int base = blockIdx.x * (256 * BIN_EPT) + threadIdx.x;
    int key[BIN_EPT], bkt[BIN_EPT];
#pragma unroll
    for (int j = 0; j < BIN_EPT; ++j) {
        int idx = base + j * 256;
        bkt[j] = -1;
        if (idx < E) {
            int d = dst[idx];
            int sV = src[idx];
            bkt[j] = d >> 10;
            key[j] = (sV << 10) | (d & 1023);
            atomicAdd(&hist[bkt[j]], 1);
        }
    }
    __syncthreads();
    int c = hist[threadIdx.x];
    basew[threadIdx.x] = c ? atomicAdd(&bucketCursor[threadIdx.x], c) : 0;
    __syncthreads();
#pragma unroll
    for (int j = 0; j < BIN_EPT; ++j) {
        if (bkt[j] >= 0) {
            int r = atomicAdd(&rank[bkt[j]], 1);
            binned[basew[bkt[j]] + r] = key[j];
        }
    }
}

// ------- per-bucket CSR fill: block b owns nodes [b*1024,(b+1)*1024) -------
// outputs: degi[node], cursor[node]=row end (global), csr[] grouped per node
__global__ __launch_bounds__(256) void bucket_fill(const int* __restrict__ binned,
                                                   const int* __restrict__ bucketBase,
                                                   const int* __restrict__ bucketCount,
                                                   int* __restrict__ degi, int* __restrict__ cursor,
                                                   int* __restrict__ csr, int N) {
    int b = blockIdx.x;
    int nodeBase = b << 10;
    if (nodeBase >= N) return;
    int s = bucketBase[b];
    int e = s + bucketCount[b];
    __shared__ int h[1024];
    __shared__ int s2[256];
    int t = threadIdx.x;
    int i0 = t * 4;
#pragma unroll
    for (int j = 0; j < 4; ++j) h[i0 + j] = 0;
    __syncthreads();
    for (int k = s + t; k < e; k += 256)
        atomicAdd(&h[binned[k] & 1023], 1);
    __syncthreads();
    int v[4];
#pragma unroll
    for (int j = 0; j < 4; ++j) {
        v[j] = h[i0 + j];
        int node = nodeBase + i0 + j;
        if (node < N) degi[node] = v[j];
    }
    s2[t] = v[0] + v[1] + v[2] + v[3];
    __syncthreads();
    for (int off = 1; off < 256; off <<= 1) {
        int x = (t >= off) ? s2[t - off] : 0;
        __syncthreads();
        s2[t] += x;
        __syncthreads();
    }
    int pre = (t > 0) ? s2[t - 1] : 0;
    h[i0]     = pre;
    h[i0 + 1] = pre + v[0];
    h[i0 + 2] = pre + v[0] + v[1];
    h[i0 + 3] = pre + v[0] + v[1] + v[2];
    __syncthreads();
    for (int k = s + t; k < e; k += 256) {
        int key = binned[k];
        int p = atomicAdd(&h[key & 1023], 1);
        csr[s + p] = key >> 10;
    }
    __syncthreads();
#pragma unroll
    for (int j = 0; j < 4; ++j) {
        int node = nodeBase + i0 + j;
        if (node < N) cursor[node] = s + h[i0 + j];   // = start + deg = row end
    }
}

// ---------------- fallback degree histogram ----------------
__global__ void hist_kernel(const int* __restrict__ dst, int* __restrict__ degi, int E) {
    int e = blockIdx.x * blockDim.x + threadIdx.x;
    if (e < E) atomicAdd(&degi[dst[e]], 1);
}

// ------------- layer1: P = dinv * (emb[x] @ W1); optional dup into Q -------------
__global__ __launch_bounds__(256) void embed_gemm1(
        const int* __restrict__ x, const float* __restrict__ emb,
        const float* __restrict__ W1, const int* __restrict__ degi,
        float* __restrict__ P, float* __restrict__ Qdup, int N) {
    __shared__ float sW[D * D];
    for (int j = threadIdx.x; j < D * D; j += blockDim.x) sW[j] = W1[j];
    __syncthreads();
    int i = blockIdx.x * blockDim.x + threadIdx.x;
    if (i >= N) return;
    const float* er = emb + (size_t)x[i] * D;
    float t[D];
#pragma unroll
    for (int k = 0; k < D; ++k) t[k] = er[k];
    float dinv = rsqrtf((float)degi[i] + 1.0f);
#pragma unroll
    for (int d = 0; d < D; ++d) {
        float acc = 0.0f;
#pragma unroll
        for (int k = 0; k < D; ++k) acc = fmaf(t[k], sW[k * D + d], acc);
        float v = dinv * acc;
        P[i * D + d] = v;
        if (Qdup) Qdup[i * D + d] = v;
    }
}

// ------- gather + finish: Q[i] = dinv_i * (P[i] + sum_{s in nbrs(i)} P[s]) + bias -------
__global__ __launch_bounds__(256) void gather_finish(
        const int* __restrict__ csr, const int* __restrict__ cursor,
        const int* __restrict__ degi, const float* __restrict__ P,
        const float* __restrict__ bias, float* __restrict__ Q, int N) {
    int idx = blockIdx.x * blockDim.x + threadIdx.x;
    int node = idx >> 5;
    int lane = idx & 31;
    if (node >= N) return;
    bool act = (lane < D);
    int end = cursor[node];
    int dg = degi[node];
    int start = end - dg;
    float acc = act ? P[node * D + lane] : 0.0f;   // self loop
    int k = start;
    while (k + 2 <= end) {
        int s0 = csr[k];
        int s1 = csr[k + 1];
        float v0 = act ? P[s0 * D + lane] : 0.0f;
        float v1 = act ? P[s1 * D + lane] : 0.0f;
        acc += v0 + v1;
        k += 2;
    }
    if (k < end) {
        int s0 = csr[k];
        acc += act ? P[s0 * D + lane] : 0.0f;
    }
    if (act) {
        float dinv = rsqrtf((float)dg + 1.0f);
        Q[node * D + lane] = fmaf(dinv, acc, bias[lane]);
    }
}

// ---------------- fallback scatter (atomics) ----------------
__global__ void scatter_kernel(const int* __restrict__ src, const int* __restrict__ dst,
                               const float* __restrict__ A, float* __restrict__ B, int E) {
    int idx = blockIdx.x * blockDim.x + threadIdx.x;
    int e = idx >> 5;
    int lane = idx & 31;
    if (e >= E || lane >= D) return;
    atomicAdd(&B[dst[e] * D + lane], A[src[e] * D + lane]);
}

// ---------------- fallback transform: Q = dinv*Q + bias ----------------
__global__ __launch_bounds__(256) void transform_kernel(
        float* __restrict__ Q, const int* __restrict__ degi,
        const float* __restrict__ bias, int N) {
    int i = blockIdx.x * blockDim.x + threadIdx.x;
    if (i >= N) return;
    float dinv = rsqrtf((float)degi[i] + 1.0f);
#pragma unroll
    for (int d = 0; d < D; ++d)
        Q[i * D + d] = fmaf(dinv, Q[i * D + d], bias[d]);
}

// ---------------- stats over Q: st[0..24]=sum, st[25..49]=sumsq ----------------
__global__ __launch_bounds__(256) void stats_kernel(
        const float* __restrict__ Q, float* __restrict__ st, int N) {
    float ls[D], lq[D];
#pragma unroll
    for (int d = 0; d < D; ++d) { ls[d] = 0.0f; lq[d] = 0.0f; }
    for (int i = blockIdx.x * blockDim.x + threadIdx.x; i < N;
         i += gridDim.x * blockDim.x) {
#pragma unroll
        for (int d = 0; d < D; ++d) {
            float v = Q[i * D + d];
            ls[d] += v;
            lq[d] += v * v;
        }
    }
#pragma unroll
    for (int d = 0; d < D; ++d) {
        for (int off = 32; off > 0; off >>= 1) {
            ls[d] += __shfl_down(ls[d], off, 64);
            lq[d] += __shfl_down(lq[d], off, 64);
        }
    }
    __shared__ float red[4][2 * D];
    int wave = threadIdx.x >> 6;
    int lane = threadIdx.x & 63;
    if (lane == 0) {
#pragma unroll
        for (int d = 0; d < D; ++d) {
            red[wave][d] = ls[d];
            red[wave][D + d] = lq[d];
        }
    }
    __syncthreads();
    if (threadIdx.x < 2 * D) {
        float t = red[0][threadIdx.x] + red[1][threadIdx.x] +
                  red[2][threadIdx.x] + red[3][threadIdx.x];
        atomicAdd(&st[threadIdx.x], t);
    }
}

// ---------------- mu / rstd ----------------
__global__ void musig_kernel(const float* __restrict__ sum, const float* __restrict__ sq,
                             float* __restrict__ mu, float* __restrict__ rstd, float invN) {
    int d = threadIdx.x;
    if (d < D) {
        float m = sum[d] * invN;
        float v = fmaxf(sq[d] * invN - m * m, 0.0f);
        mu[d] = m;
        rstd[d] = rsqrtf(v + 1e-5f);
    }
}

// ------- layer2: t = relu(bn(Q)); P = dinv*(t@W2); optional dup -------
__global__ __launch_bounds__(256) void bn_gemm(
        const float* __restrict__ Qin,
        const float* __restrict__ mu, const float* __restrict__ rstd,
        const float* __restrict__ g, const float* __restrict__ be,
        const float* __restrict__ W, const int* __restrict__ degi,
        float* __restrict__ P, float* __restrict__ Qdup, int N) {
    __shared__ float sW[D * D];
    __shared__ float sScale[D], sShift[D];
    for (int j = threadIdx.x; j < D * D; j += blockDim.x) sW[j] = W[j];
    if (threadIdx.x < D) {
        float sc = rstd[threadIdx.x] * g[threadIdx.x];
        sScale[threadIdx.x] = sc;
        sShift[threadIdx.x] = be[threadIdx.x] - mu[threadIdx.x] * sc;
    }
    __syncthreads();
    int i = blockIdx.x * blockDim.x + threadIdx.x;
    if (i >= N) return;
    float t[D];
#pragma unroll
    for (int d = 0; d < D; ++d)
        t[d] = fmaxf(0.0f, fmaf(Qin[i * D + d], sScale[d], sShift[d]));
    float dinv = rsqrtf((float)degi[i] + 1.0f);
#pragma unroll
    for (int d = 0; d < D; ++d) {
        float acc = 0.0f;
#pragma unroll
        for (int k = 0; k < D; ++k) acc = fmaf(t[k], sW[k * D + d], acc);
        float v = dinv * acc;
        P[i * D + d] = v;
        if (Qdup) Qdup[i * D + d] = v;
    }
}

// ------- head: t = relu(bn(Q)); m = relu(t@Wm1+bm1); out = sigmoid(m@Wm2+bm2) -------
__global__ __launch_bounds__(256) void final_kernel(
        const float* __restrict__ Q,
        const float* __restrict__ mu, const float* __restrict__ rstd,
        const float* __restrict__ g, const float* __restrict__ be,
        const float* __restrict__ Wm1, const float* __restrict__ bm1,
        const float* __restrict__ Wm2, const float* __restrict__ bm2,
        float* __restrict__ out, int N) {
    __shared__ float sW1[D * 12];
    __shared__ float sb1[12], sW2[12];
    __shared__ float sScale[D], sShift[D];
    __shared__ float sb2;
    for (int j = threadIdx.x; j < D * 12; j += blockDim.x) sW1[j] = Wm1[j];
    if (threadIdx.x < 12) {
        sb1[threadIdx.x] = bm1[threadIdx.x];
        sW2[threadIdx.x] = Wm2[threadIdx.x];
    }
    if (threadIdx.x < D) {
        float sc = rstd[threadIdx.x] * g[threadIdx.x];
        sScale[threadIdx.x] = sc;
        sShift[threadIdx.x] = be[threadIdx.x] - mu[threadIdx.x] * sc;
    }
    if (threadIdx.x == 0) sb2 = bm2[0];
    __syncthreads();
    int i = blockIdx.x * blockDim.x + threadIdx.x;
    if (i >= N) return;
    float t[D];
#pragma unroll
    for (int d = 0; d < D; ++d)
        t[d] = fmaxf(0.0f, fmaf(Q[i * D + d], sScale[d], sShift[d]));
    float z = sb2;
#pragma unroll
    for (int j = 0; j < 12; ++j) {
        float m = sb1[j];
#pragma unroll
        for (int k = 0; k < D; ++k) m = fmaf(t[k], sW1[k * 12 + j], m);
        m = fmaxf(0.0f, m);
        z = fmaf(m, sW2[j], z);
    }
    out[i] = 1.0f / (1.0f + expf(-z));
}

extern "C" void kernel_launch(void* const* d_in, const int* in_sizes, int n_in,
                              void* d_out, int out_size, void* d_ws, size_t ws_size,
                              hipStream_t stream) {
    const int*   x    = (const int*)d_in[0];
    const int*   ei   = (const int*)d_in[1];
    const float* emb  = (const float*)d_in[2];
    const float* W1   = (const float*)d_in[3];
    const float* b1   = (const float*)d_in[4];
    const float* g1   = (const float*)d_in[5];
    const float* be1  = (const float*)d_in[6];
    const float* W2   = (const float*)d_in[7];
    const float* b2   = (const float*)d_in[8];
    const float* g2   = (const float*)d_in[9];
    const float* be2  = (const float*)d_in[10];
    const float* Wm1  = (const float*)d_in[11];
    const float* bm1  = (const float*)d_in[12];
    const float* Wm2  = (const float*)d_in[13];
    const float* bm2  = (const float*)d_in[14];
    float* out = (float*)d_out;

    int N = in_sizes[0];
    int E = in_sizes[1] / 2;
    const int* src = ei;
    const int* dst = ei + E;

    size_t csrNeed = ((size_t)2 * N + E + 3 * NBK + (size_t)50 * N + 200) * 4;
    bool useCSR = (ws_size >= csrNeed) && (N <= NBK * 1024);

    int nbN  = (N + 255) / 256;
    int nbE  = (E + 255) / 256;
    int nbG  = (int)(((long)N * 32 + 255) / 256);
    int nbS  = (int)(((long)E * 32 + 255) / 256);

    if (useCSR) {
        int*   degi    = (int*)d_ws;                // N
        int*   cursor  = degi + N;                  // N
        int*   csr     = cursor + N;                // E
        int*   bCount  = csr + E;                   // 256
        int*   bBase   = bCount + NBK;              // 256
        int*   bCursor = bBase + NBK;               // 256
        float* P       = (float*)(bCursor + NBK);   // N*D
        float* Q       = P + (size_t)N * D;         // N*D
        float* stats   = Q + (size_t)N * D;         // 200
        int*   binned  = (int*)Q;                   // E (aliases Q; dead before Q written)
        float* st1 = stats;       float* st2 = stats + 50;
        float* mu1 = stats + 100; float* rs1 = stats + 125;
        float* mu2 = stats + 150; float* rs2 = stats + 175;

        hipMemsetAsync(bCount, 0, NBK * sizeof(int), stream);
        hipMemsetAsync(stats, 0, 100 * sizeof(float), stream);

        int nbBin = (E + 256 * BIN_EPT - 1) / (256 * BIN_EPT);
        int nbBkt = (N + 1023) / 1024;

        bucket_hist<<<512, 256, 0, stream>>>(dst, bCount, E);
        bucket_scan<<<1, 256, 0, stream>>>(bCount, bBase, bCursor);
        bin_edges<<<nbBin, 256, 0, stream>>>(src, dst, bCursor, binned, E);
        bucket_fill<<<nbBkt, 256, 0, stream>>>(binned, bBase, bCount, degi, cursor, csr, N);
        embed_gemm1<<<nbN, 256, 0, stream>>>(x, emb, W1, degi, P, nullptr, N);
        gather_finish<<<nbG, 256, 0, stream>>>(csr, cursor, degi, P, b1, Q, N);
        stats_kernel<<<STATS_BLOCKS, 256, 0, stream>>>(Q, st1, N);
        musig_kernel<<<1, 64, 0, stream>>>(st1, st1 + 25, mu1, rs1, 1.0f / (float)N);
        bn_gemm<<<nbN, 256, 0, stream>>>(Q, mu1, rs1, g1, be1, W2, degi, P, nullptr, N);
        gather_finish<<<nbG, 256, 0, stream>>>(csr, cursor, degi, P, b2, Q, N);
        stats_kernel<<<STATS_BLOCKS, 256, 0, stream>>>(Q, st2, N);
        musig_kernel<<<1, 64, 0, stream>>>(st2, st2 + 25, mu2, rs2, 1.0f / (float)N);
        final_kernel<<<nbN, 256, 0, stream>>>(Q, mu2, rs2, g2, be2, Wm1, bm1, Wm2, bm2, out, N);
    } else {
        // fallback: atomic-scatter path
        int*   degi  = (int*)d_ws;                  // N
        float* P     = (float*)(degi + N);          // N*D
        float* Q     = P + (size_t)N * D;           // N*D
        float* stats = Q + (size_t)N * D;           // 200
        float* st1 = stats;       float* st2 = stats + 50;
        float* mu1 = stats + 100; float* rs1 = stats + 125;
        float* mu2 = stats + 150; float* rs2 = stats + 175;

        hipMemsetAsync(degi, 0, (size_t)N * sizeof(int), stream);
        hipMemsetAsync(stats, 0, 100 * sizeof(float), stream);

        hist_kernel<<<nbE, 256, 0, stream>>>(dst, degi, E);
        embed_gemm1<<<nbN, 256, 0, stream>>>(x, emb, W1, degi, P, Q, N);
        scatter_kernel<<<nbS, 256, 0, stream>>>(src, dst, P, Q, E);
        transform_kernel<<<nbN, 256, 0, stream>>>(Q, degi, b1, N);
        stats_kernel<<<STATS_BLOCKS, 256, 0, stream>>>(Q, st1, N);
        musig_kernel<<<1, 64, 0, stream>>>(st1, st1 + 25, mu1, rs1, 1.0f / (float)N);
        bn_gemm<<<nbN, 256, 0, stream>>>(Q, mu1, rs1, g1, be1, W2, degi, P, Q, N);
        scatter_kernel<<<nbS, 256, 0, stream>>>(src, dst, P, Q, E);
        transform_kernel<<<nbN, 256, 0, stream>>>(Q, degi, b2, N);
        stats_kernel<<<STATS_BLOCKS, 256, 0, stream>>>(Q, st2, N);
        musig_kernel<<<1, 64, 0, stream>>>(st2, st2 + 25, mu2, rs2, 1.0f / (float)N);
        final_kernel<<<nbN, 256, 0, stream>>>(Q, mu2, rs2, g2, be2, Wm1, bm1, Wm2, bm2, out, N);
    }
}

// Round 5
// 430.962 us; speedup vs baseline: 6.6608x; 1.4112x over previous
//
#include <hip/hip_runtime.h>
#include <hip/hip_fp16.h>
#include <math.h>

#define D 25
#define PH_STRIDE 32   // fp16 row padded to 32 elems = 64 B = one cache line
#define STATS_BLOCKS 512
#define NBK 256        // max buckets (1024 nodes each)
#define BIN_EPT 16     // edges per thread in bin_edges

// ---------------- bucket histogram: count[b] = #edges with dst>>10 == b ----------------
__global__ __launch_bounds__(256) void bucket_hist(const int* __restrict__ dst,
                                                   int* __restrict__ bucketCount, int E) {
    __shared__ int h[NBK];
    h[threadIdx.x] = 0;
    __syncthreads();
    for (int e = blockIdx.x * blockDim.x + threadIdx.x; e < E; e += gridDim.x * blockDim.x)
        atomicAdd(&h[dst[e] >> 10], 1);
    __syncthreads();
    int c = h[threadIdx.x];
    if (c) atomicAdd(&bucketCount[threadIdx.x], c);
}

// ---------------- exclusive scan of bucket counts (1 block, 256 threads) ----------------
__global__ void bucket_scan(const int* __restrict__ bucketCount,
                            int* __restrict__ bucketBase, int* __restrict__ bucketCursor) {
    __shared__ int s[NBK];
    int t = threadIdx.x;
    s[t] = bucketCount[t];
    __syncthreads();
    for (int off = 1; off < NBK; off <<= 1) {
        int x = (t >= off) ? s[t - off] : 0;
        __syncthreads();
        s[t] += x;
        __syncthreads();
    }
    int base = (t > 0) ? s[t - 1] : 0;
    bucketBase[t] = base;
    bucketCursor[t] = base;
}

// ------- binning: binned[] gets keys (src<<10 | dst&1023) grouped by bucket -------
__global__ __launch_bounds__(256) void bin_edges(const int* __restrict__ src,
                                                 const int* __restrict__ dst,
                                                 int* __restrict__ bucketCursor,
                                                 int* __restrict__ binned, int E) {
    __shared__ int hist[NBK], rank[NBK], basew[NBK];
    hist[threadIdx.x] = 0;
    rank[threadIdx.x] = 0;
    __syncthreads();
    int base = blockIdx.x * (256 * BIN_EPT) + threadIdx.x;
    int key[BIN_EPT], bkt[BIN_EPT];
#pragma unroll
    for (int j = 0; j < BIN_EPT; ++j) {
        int idx = base + j * 256;
        bkt[j] = -1;
        if (idx < E) {
            int d = dst[idx];
            int sV = src[idx];
            bkt[j] = d >> 10;
            key[j] = (sV << 10) | (d & 1023);
            atomicAdd(&hist[bkt[j]], 1);
        }
    }
    __syncthreads();
    int c = hist[threadIdx.x];
    basew[threadIdx.x] = c ? atomicAdd(&bucketCursor[threadIdx.x], c) : 0;
    __syncthreads();
#pragma unroll
    for (int j = 0; j < BIN_EPT; ++j) {
        if (bkt[j] >= 0) {
            int r = atomicAdd(&rank[bkt[j]], 1);
            binned[basew[bkt[j]] + r] = key[j];
        }
    }
}

// ------- per-bucket CSR fill: block b owns nodes [b*1024,(b+1)*1024) -------
__global__ __launch_bounds__(256) void bucket_fill(const int* __restrict__ binned,
                                                   const int* __restrict__ bucketBase,
                                                   const int* __restrict__ bucketCount,
                                                   int* __restrict__ degi, int* __restrict__ cursor,
                                                   int* __restrict__ csr, int N) {
    int b = blockIdx.x;
    int nodeBase = b << 10;
    if (nodeBase >= N) return;
    int s = bucketBase[b];
    int e = s + bucketCount[b];
    __shared__ int h[1024];
    __shared__ int s2[256];
    int t = threadIdx.x;
    int i0 = t * 4;
#pragma unroll
    for (int j = 0; j < 4; ++j) h[i0 + j] = 0;
    __syncthreads();
    for (int k = s + t; k < e; k += 256)
        atomicAdd(&h[binned[k] & 1023], 1);
    __syncthreads();
    int v[4];
#pragma unroll
    for (int j = 0; j < 4; ++j) {
        v[j] = h[i0 + j];
        int node = nodeBase + i0 + j;
        if (node < N) degi[node] = v[j];
    }
    s2[t] = v[0] + v[1] + v[2] + v[3];
    __syncthreads();
    for (int off = 1; off < 256; off <<= 1) {
        int x = (t >= off) ? s2[t - off] : 0;
        __syncthreads();
        s2[t] += x;
        __syncthreads();
    }
    int pre = (t > 0) ? s2[t - 1] : 0;
    h[i0]     = pre;
    h[i0 + 1] = pre + v[0];
    h[i0 + 2] = pre + v[0] + v[1];
    h[i0 + 3] = pre + v[0] + v[1] + v[2];
    __syncthreads();
    for (int k = s + t; k < e; k += 256) {
        int key = binned[k];
        int p = atomicAdd(&h[key & 1023], 1);
        csr[s + p] = key >> 10;
    }
    __syncthreads();
#pragma unroll
    for (int j = 0; j < 4; ++j) {
        int node = nodeBase + i0 + j;
        if (node < N) cursor[node] = s + h[i0 + j];   // row end
    }
}

// ---------------- fallback degree histogram ----------------
__global__ void hist_kernel(const int* __restrict__ dst, int* __restrict__ degi, int E) {
    int e = blockIdx.x * blockDim.x + threadIdx.x;
    if (e < E) atomicAdd(&degi[dst[e]], 1);
}

// ------------- layer1 (fp16 rows): Ph = half(dinv * (emb[x] @ W1)), stride 32 -------------
__global__ __launch_bounds__(256) void embed_gemm1_h(
        const int* __restrict__ x, const float* __restrict__ emb,
        const float* __restrict__ W1, const int* __restrict__ degi,
        __half* __restrict__ Ph, int N) {
    __shared__ float sW[D * D];
    for (int j = threadIdx.x; j < D * D; j += blockDim.x) sW[j] = W1[j];
    __syncthreads();
    int i = blockIdx.x * blockDim.x + threadIdx.x;
    if (i >= N) return;
    const float* er = emb + (size_t)x[i] * D;
    float t[D];
#pragma unroll
    for (int k = 0; k < D; ++k) t[k] = er[k];
    float dinv = rsqrtf((float)degi[i] + 1.0f);
    __half* row = Ph + (size_t)i * PH_STRIDE;
#pragma unroll
    for (int d = 0; d < D; ++d) {
        float acc = 0.0f;
#pragma unroll
        for (int k = 0; k < D; ++k) acc = fmaf(t[k], sW[k * D + d], acc);
        row[d] = __float2half(dinv * acc);
    }
}

// ------- gather (fp16 rows): Q[i] = dinv_i * (Ph[i] + sum_nbrs Ph[s]) + bias -------
// 32 lanes per node; each row is one aligned 64B line.
__global__ __launch_bounds__(256) void gather_finish_h(
        const int* __restrict__ csr, const int* __restrict__ cursor,
        const int* __restrict__ degi, const __half* __restrict__ Ph,
        const float* __restrict__ bias, float* __restrict__ Q, int N) {
    int idx = blockIdx.x * blockDim.x + threadIdx.x;
    int node = idx >> 5;
    int lane = idx & 31;
    if (node >= N) return;
    int end = cursor[node];
    int dg = degi[node];
    int k = end - dg;
    float acc = __half2float(Ph[(size_t)node * PH_STRIDE + lane]);  // self loop
    while (k + 4 <= end) {
        int s0 = csr[k], s1 = csr[k + 1], s2 = csr[k + 2], s3 = csr[k + 3];
        float v0 = __half2float(Ph[(size_t)s0 * PH_STRIDE + lane]);
        float v1 = __half2float(Ph[(size_t)s1 * PH_STRIDE + lane]);
        float v2 = __half2float(Ph[(size_t)s2 * PH_STRIDE + lane]);
        float v3 = __half2float(Ph[(size_t)s3 * PH_STRIDE + lane]);
        acc += (v0 + v1) + (v2 + v3);
        k += 4;
    }
    while (k < end) {
        acc += __half2float(Ph[(size_t)csr[k] * PH_STRIDE + lane]);
        ++k;
    }
    if (lane < D) {
        float dinv = rsqrtf((float)dg + 1.0f);
        Q[(size_t)node * D + lane] = fmaf(dinv, acc, bias[lane]);
    }
}

// ------- layer2 (fp16 rows): t = relu(bn(Q)); Ph = half(dinv*(t@W2)) -------
__global__ __launch_bounds__(256) void bn_gemm_h(
        const float* __restrict__ Qin,
        const float* __restrict__ mu, const float* __restrict__ rstd,
        const float* __restrict__ g, const float* __restrict__ be,
        const float* __restrict__ W, const int* __restrict__ degi,
        __half* __restrict__ Ph, int N) {
    __shared__ float sW[D * D];
    __shared__ float sScale[D], sShift[D];
    for (int j = threadIdx.x; j < D * D; j += blockDim.x) sW[j] = W[j];
    if (threadIdx.x < D) {
        float sc = rstd[threadIdx.x] * g[threadIdx.x];
        sScale[threadIdx.x] = sc;
        sShift[threadIdx.x] = be[threadIdx.x] - mu[threadIdx.x] * sc;
    }
    __syncthreads();
    int i = blockIdx.x * blockDim.x + threadIdx.x;
    if (i >= N) return;
    float t[D];
#pragma unroll
    for (int d = 0; d < D; ++d)
        t[d] = fmaxf(0.0f, fmaf(Qin[i * D + d], sScale[d], sShift[d]));
    float dinv = rsqrtf((float)degi[i] + 1.0f);
    __half* row = Ph + (size_t)i * PH_STRIDE;
#pragma unroll
    for (int d = 0; d < D; ++d) {
        float acc = 0.0f;
#pragma unroll
        for (int k = 0; k < D; ++k) acc = fmaf(t[k], sW[k * D + d], acc);
        row[d] = __float2half(dinv * acc);
    }
}

// ---------------- fp32 fallback kernels (atomic-scatter path) ----------------
__global__ __launch_bounds__(256) void embed_gemm1(
        const int* __restrict__ x, const float* __restrict__ emb,
        const float* __restrict__ W1, const int* __restrict__ degi,
        float* __restrict__ P, float* __restrict__ Qdup, int N) {
    __shared__ float sW[D * D];
    for (int j = threadIdx.x; j < D * D; j += blockDim.x) sW[j] = W1[j];
    __syncthreads();
    int i = blockIdx.x * blockDim.x + threadIdx.x;
    if (i >= N) return;
    const float* er = emb + (size_t)x[i] * D;
    float t[D];
#pragma unroll
    for (int k = 0; k < D; ++k) t[k] = er[k];
    float dinv = rsqrtf((float)degi[i] + 1.0f);
#pragma unroll
    for (int d = 0; d < D; ++d) {
        float acc = 0.0f;
#pragma unroll
        for (int k = 0; k < D; ++k) acc = fmaf(t[k], sW[k * D + d], acc);
        float v = dinv * acc;
        P[i * D + d] = v;
        if (Qdup) Qdup[i * D + d] = v;
    }
}

__global__ void scatter_kernel(const int* __restrict__ src, const int* __restrict__ dst,
                               const float* __restrict__ A, float* __restrict__ B, int E) {
    int idx = blockIdx.x * blockDim.x + threadIdx.x;
    int e = idx >> 5;
    int lane = idx & 31;
    if (e >= E || lane >= D) return;
    atomicAdd(&B[dst[e] * D + lane], A[src[e] * D + lane]);
}

__global__ __launch_bounds__(256) void transform_kernel(
        float* __restrict__ Q, const int* __restrict__ degi,
        const float* __restrict__ bias, int N) {
    int i = blockIdx.x * blockDim.x + threadIdx.x;
    if (i >= N) return;
    float dinv = rsqrtf((float)degi[i] + 1.0f);
#pragma unroll
    for (int d = 0; d < D; ++d)
        Q[i * D + d] = fmaf(dinv, Q[i * D + d], bias[d]);
}

__global__ __launch_bounds__(256) void bn_gemm(
        const float* __restrict__ Qin,
        const float* __restrict__ mu, const float* __restrict__ rstd,
        const float* __restrict__ g, const float* __restrict__ be,
        const float* __restrict__ W, const int* __restrict__ degi,
        float* __restrict__ P, float* __restrict__ Qdup, int N) {
    __shared__ float sW[D * D];
    __shared__ float sScale[D], sShift[D];
    for (int j = threadIdx.x; j < D * D; j += blockDim.x) sW[j] = W[j];
    if (threadIdx.x < D) {
        float sc = rstd[threadIdx.x] * g[threadIdx.x];
        sScale[threadIdx.x] = sc;
        sShift[threadIdx.x] = be[threadIdx.x] - mu[threadIdx.x] * sc;
    }
    __syncthreads();
    int i = blockIdx.x * blockDim.x + threadIdx.x;
    if (i >= N) return;
    float t[D];
#pragma unroll
    for (int d = 0; d < D; ++d)
        t[d] = fmaxf(0.0f, fmaf(Qin[i * D + d], sScale[d], sShift[d]));
    float dinv = rsqrtf((float)degi[i] + 1.0f);
#pragma unroll
    for (int d = 0; d < D; ++d) {
        float acc = 0.0f;
#pragma unroll
        for (int k = 0; k < D; ++k) acc = fmaf(t[k], sW[k * D + d], acc);
        float v = dinv * acc;
        P[i * D + d] = v;
        if (Qdup) Qdup[i * D + d] = v;
    }
}

// ---------------- stats over Q: st[0..24]=sum, st[25..49]=sumsq ----------------
__global__ __launch_bounds__(256) void stats_kernel(
        const float* __restrict__ Q, float* __restrict__ st, int N) {
    float ls[D], lq[D];
#pragma unroll
    for (int d = 0; d < D; ++d) { ls[d] = 0.0f; lq[d] = 0.0f; }
    for (int i = blockIdx.x * blockDim.x + threadIdx.x; i < N;
         i += gridDim.x * blockDim.x) {
#pragma unroll
        for (int d = 0; d < D; ++d) {
            float v = Q[i * D + d];
            ls[d] += v;
            lq[d] += v * v;
        }
    }
#pragma unroll
    for (int d = 0; d < D; ++d) {
        for (int off = 32; off > 0; off >>= 1) {
            ls[d] += __shfl_down(ls[d], off, 64);
            lq[d] += __shfl_down(lq[d], off, 64);
        }
    }
    __shared__ float red[4][2 * D];
    int wave = threadIdx.x >> 6;
    int lane = threadIdx.x & 63;
    if (lane == 0) {
#pragma unroll
        for (int d = 0; d < D; ++d) {
            red[wave][d] = ls[d];
            red[wave][D + d] = lq[d];
        }
    }
    __syncthreads();
    if (threadIdx.x < 2 * D) {
        float t = red[0][threadIdx.x] + red[1][threadIdx.x] +
                  red[2][threadIdx.x] + red[3][threadIdx.x];
        atomicAdd(&st[threadIdx.x], t);
    }
}

// ---------------- mu / rstd ----------------
__global__ void musig_kernel(const float* __restrict__ sum, const float* __restrict__ sq,
                             float* __restrict__ mu, float* __restrict__ rstd, float invN) {
    int d = threadIdx.x;
    if (d < D) {
        float m = sum[d] * invN;
        float v = fmaxf(sq[d] * invN - m * m, 0.0f);
        mu[d] = m;
        rstd[d] = rsqrtf(v + 1e-5f);
    }
}

// ------- head: t = relu(bn(Q)); m = relu(t@Wm1+bm1); out = sigmoid(m@Wm2+bm2) -------
__global__ __launch_bounds__(256) void final_kernel(
        const float* __restrict__ Q,
        const float* __restrict__ mu, const float* __restrict__ rstd,
        const float* __restrict__ g, const float* __restrict__ be,
        const float* __restrict__ Wm1, const float* __restrict__ bm1,
        const float* __restrict__ Wm2, const float* __restrict__ bm2,
        float* __restrict__ out, int N) {
    __shared__ float sW1[D * 12];
    __shared__ float sb1[12], sW2[12];
    __shared__ float sScale[D], sShift[D];
    __shared__ float sb2;
    for (int j = threadIdx.x; j < D * 12; j += blockDim.x) sW1[j] = Wm1[j];
    if (threadIdx.x < 12) {
        sb1[threadIdx.x] = bm1[threadIdx.x];
        sW2[threadIdx.x] = Wm2[threadIdx.x];
    }
    if (threadIdx.x < D) {
        float sc = rstd[threadIdx.x] * g[threadIdx.x];
        sScale[threadIdx.x] = sc;
        sShift[threadIdx.x] = be[threadIdx.x] - mu[threadIdx.x] * sc;
    }
    if (threadIdx.x == 0) sb2 = bm2[0];
    __syncthreads();
    int i = blockIdx.x * blockDim.x + threadIdx.x;
    if (i >= N) return;
    float t[D];
#pragma unroll
    for (int d = 0; d < D; ++d)
        t[d] = fmaxf(0.0f, fmaf(Q[i * D + d], sScale[d], sShift[d]));
    float z = sb2;
#pragma unroll
    for (int j = 0; j < 12; ++j) {
        float m = sb1[j];
#pragma unroll
        for (int k = 0; k < D; ++k) m = fmaf(t[k], sW1[k * 12 + j], m);
        m = fmaxf(0.0f, m);
        z = fmaf(m, sW2[j], z);
    }
    out[i] = 1.0f / (1.0f + expf(-z));
}

extern "C" void kernel_launch(void* const* d_in, const int* in_sizes, int n_in,
                              void* d_out, int out_size, void* d_ws, size_t ws_size,
                              hipStream_t stream) {
    const int*   x    = (const int*)d_in[0];
    const int*   ei   = (const int*)d_in[1];
    const float* emb  = (const float*)d_in[2];
    const float* W1   = (const float*)d_in[3];
    const float* b1   = (const float*)d_in[4];
    const float* g1   = (const float*)d_in[5];
    const float* be1  = (const float*)d_in[6];
    const float* W2   = (const float*)d_in[7];
    const float* b2   = (const float*)d_in[8];
    const float* g2   = (const float*)d_in[9];
    const float* be2  = (const float*)d_in[10];
    const float* Wm1  = (const float*)d_in[11];
    const float* bm1  = (const float*)d_in[12];
    const float* Wm2  = (const float*)d_in[13];
    const float* bm2  = (const float*)d_in[14];
    float* out = (float*)d_out;

    int N = in_sizes[0];
    int E = in_sizes[1] / 2;
    const int* src = ei;
    const int* dst = ei + E;

    // words: degi N + cursor N + csr E + buckets 768 + Ph N*16 + Q N*25 + stats 200
    size_t csrNeed = ((size_t)43 * N + E + 3 * NBK + 200) * 4;
    bool useCSR = (ws_size >= csrNeed) && (N <= NBK * 1024);

    int nbN  = (N + 255) / 256;
    int nbE  = (E + 255) / 256;
    int nbG  = (int)(((long)N * 32 + 255) / 256);
    int nbS  = (int)(((long)E * 32 + 255) / 256);

    if (useCSR) {
        int*    degi    = (int*)d_ws;                // N
        int*    cursor  = degi + N;                  // N
        int*    csr     = cursor + N;                // E
        int*    bCount  = csr + E;                   // 256
        int*    bBase   = bCount + NBK;              // 256
        int*    bCursor = bBase + NBK;               // 256
        __half* Ph      = (__half*)(bCursor + NBK);  // N*32 halves (N*16 words)
        float*  Q       = (float*)(Ph + (size_t)N * PH_STRIDE);  // N*25
        float*  stats   = Q + (size_t)N * D;         // 200
        int*    binned  = (int*)Q;                   // E ints (aliases Q; dead before Q written)
        float* st1 = stats;       float* st2 = stats + 50;
        float* mu1 = stats + 100; float* rs1 = stats + 125;
        float* mu2 = stats + 150; float* rs2 = stats + 175;

        hipMemsetAsync(bCount, 0, NBK * sizeof(int), stream);
        hipMemsetAsync(stats, 0, 100 * sizeof(float), stream);

        int nbBin = (E + 256 * BIN_EPT - 1) / (256 * BIN_EPT);
        int nbBkt = (N + 1023) / 1024;

        bucket_hist<<<512, 256, 0, stream>>>(dst, bCount, E);
        bucket_scan<<<1, 256, 0, stream>>>(bCount, bBase, bCursor);
        bin_edges<<<nbBin, 256, 0, stream>>>(src, dst, bCursor, binned, E);
        bucket_fill<<<nbBkt, 256, 0, stream>>>(binned, bBase, bCount, degi, cursor, csr, N);
        embed_gemm1_h<<<nbN, 256, 0, stream>>>(x, emb, W1, degi, Ph, N);
        gather_finish_h<<<nbG, 256, 0, stream>>>(csr, cursor, degi, Ph, b1, Q, N);
        stats_kernel<<<STATS_BLOCKS, 256, 0, stream>>>(Q, st1, N);
        musig_kernel<<<1, 64, 0, stream>>>(st1, st1 + 25, mu1, rs1, 1.0f / (float)N);
        bn_gemm_h<<<nbN, 256, 0, stream>>>(Q, mu1, rs1, g1, be1, W2, degi, Ph, N);
        gather_finish_h<<<nbG, 256, 0, stream>>>(csr, cursor, degi, Ph, b2, Q, N);
        stats_kernel<<<STATS_BLOCKS, 256, 0, stream>>>(Q, st2, N);
        musig_kernel<<<1, 64, 0, stream>>>(st2, st2 + 25, mu2, rs2, 1.0f / (float)N);
        final_kernel<<<nbN, 256, 0, stream>>>(Q, mu2, rs2, g2, be2, Wm1, bm1, Wm2, bm2, out, N);
    } else {
        // fallback: fp32 atomic-scatter path
        int*   degi  = (int*)d_ws;                  // N
        float* P     = (float*)(degi + N);          // N*D
        float* Q     = P + (size_t)N * D;           // N*D
        float* stats = Q + (size_t)N * D;           // 200
        float* st1 = stats;       float* st2 = stats + 50;
        float* mu1 = stats + 100; float* rs1 = stats + 125;
        float* mu2 = stats + 150; float* rs2 = stats + 175;

        hipMemsetAsync(degi, 0, (size_t)N * sizeof(int), stream);
        hipMemsetAsync(stats, 0, 100 * sizeof(float), stream);

        hist_kernel<<<nbE, 256, 0, stream>>>(dst, degi, E);
        embed_gemm1<<<nbN, 256, 0, stream>>>(x, emb, W1, degi, P, Q, N);
        scatter_kernel<<<nbS, 256, 0, stream>>>(src, dst, P, Q, E);
        transform_kernel<<<nbN, 256, 0, stream>>>(Q, degi, b1, N);
        stats_kernel<<<STATS_BLOCKS, 256, 0, stream>>>(Q, st1, N);
        musig_kernel<<<1, 64, 0, stream>>>(st1, st1 + 25, mu1, rs1, 1.0f / (float)N);
        bn_gemm<<<nbN, 256, 0, stream>>>(Q, mu1, rs1, g1, be1, W2, degi, P, Q, N);
        scatter_kernel<<<nbS, 256, 0, stream>>>(src, dst, P, Q, E);
        transform_kernel<<<nbN, 256, 0, stream>>>(Q, degi, b2, N);
        stats_kernel<<<STATS_BLOCKS, 256, 0, stream>>>(Q, st2, N);
        musig_kernel<<<1, 64, 0, stream>>>(st2, st2 + 25, mu2, rs2, 1.0f / (float)N);
        final_kernel<<<nbN, 256, 0, stream>>>(Q, mu2, rs2, g2, be2, Wm1, bm1, Wm2, bm2, out, N);
    }
}

// Round 6
// 417.455 us; speedup vs baseline: 6.8763x; 1.0324x over previous
//
#include <hip/hip_runtime.h>
#include <hip/hip_fp16.h>
#include <math.h>

#define D 25
#define PH_STRIDE 32    // fp16 row padded to 32 elems = 64 B = one cache line
#define STATS_BLOCKS 512
#define NBK 256         // buckets of 1024 nodes
#define BIN_EDGES 8192  // edges per bin block (256 thr x 32)

// ---------------- binA: per-(block,bucket) histogram, no global atomics ----------------
__global__ __launch_bounds__(256) void binA(const int* __restrict__ dst,
                                            int* __restrict__ hist2D, int E) {
    __shared__ int h[NBK];
    h[threadIdx.x] = 0;
    __syncthreads();
    int base = blockIdx.x * BIN_EDGES;
#pragma unroll
    for (int j = 0; j < 32; ++j) {
        int idx = base + j * 256 + threadIdx.x;
        if (idx < E) atomicAdd(&h[dst[idx] >> 10], 1);
    }
    __syncthreads();
    hist2D[blockIdx.x * NBK + threadIdx.x] = h[threadIdx.x];
}

// ------- colscan: per bucket, exclusive scan over blocks (in place) + total -------
__global__ __launch_bounds__(512) void colscan(int* __restrict__ hist2D,
                                               int* __restrict__ bCount, int nbBin) {
    __shared__ int s[512];
    int b = blockIdx.x;
    int j = threadIdx.x;
    int v = (j < nbBin) ? hist2D[j * NBK + b] : 0;
    s[j] = v;
    __syncthreads();
    for (int off = 1; off < 512; off <<= 1) {
        int x = (j >= off) ? s[j - off] : 0;
        __syncthreads();
        s[j] += x;
        __syncthreads();
    }
    if (j < nbBin) hist2D[j * NBK + b] = s[j] - v;   // exclusive prefix
    if (j == 0) bCount[b] = s[511];
}

// ---------------- exclusive scan of bucket totals ----------------
__global__ void bucket_scan(const int* __restrict__ bCount, int* __restrict__ bBase) {
    __shared__ int s[NBK];
    int t = threadIdx.x;
    s[t] = bCount[t];
    __syncthreads();
    for (int off = 1; off < NBK; off <<= 1) {
        int x = (t >= off) ? s[t - off] : 0;
        __syncthreads();
        s[t] += x;
        __syncthreads();
    }
    bBase[t] = (t > 0) ? s[t - 1] : 0;
}

// ------- binB: write keys grouped by bucket using precomputed bases + LDS rank -------
__global__ __launch_bounds__(256) void binB(const int* __restrict__ src,
                                            const int* __restrict__ dst,
                                            const int* __restrict__ hist2D,
                                            const int* __restrict__ bBase,
                                            int* __restrict__ binned, int E) {
    __shared__ int rank[NBK], basew[NBK];
    int t = threadIdx.x;
    rank[t] = 0;
    basew[t] = bBase[t] + hist2D[blockIdx.x * NBK + t];
    __syncthreads();
    int base = blockIdx.x * BIN_EDGES;
#pragma unroll
    for (int j = 0; j < 32; ++j) {
        int idx = base + j * 256 + t;
        if (idx < E) {
            int d = dst[idx];
            int b = d >> 10;
            int r = atomicAdd(&rank[b], 1);
            binned[basew[b] + r] = (src[idx] << 10) | (d & 1023);
        }
    }
}

// ------- per-bucket CSR fill: block b owns nodes [b*1024,(b+1)*1024) -------
__global__ __launch_bounds__(256) void bucket_fill(const int* __restrict__ binned,
                                                   const int* __restrict__ bucketBase,
                                                   const int* __restrict__ bucketCount,
                                                   int* __restrict__ degi, int* __restrict__ cursor,
                                                   int* __restrict__ csr, int N) {
    int b = blockIdx.x;
    int nodeBase = b << 10;
    if (nodeBase >= N) return;
    int s = bucketBase[b];
    int e = s + bucketCount[b];
    __shared__ int h[1024];
    __shared__ int s2[256];
    int t = threadIdx.x;
    int i0 = t * 4;
#pragma unroll
    for (int j = 0; j < 4; ++j) h[i0 + j] = 0;
    __syncthreads();
    for (int k = s + t; k < e; k += 256)
        atomicAdd(&h[binned[k] & 1023], 1);
    __syncthreads();
    int v[4];
#pragma unroll
    for (int j = 0; j < 4; ++j) {
        v[j] = h[i0 + j];
        int node = nodeBase + i0 + j;
        if (node < N) degi[node] = v[j];
    }
    s2[t] = v[0] + v[1] + v[2] + v[3];
    __syncthreads();
    for (int off = 1; off < 256; off <<= 1) {
        int x = (t >= off) ? s2[t - off] : 0;
        __syncthreads();
        s2[t] += x;
        __syncthreads();
    }
    int pre = (t > 0) ? s2[t - 1] : 0;
    h[i0]     = pre;
    h[i0 + 1] = pre + v[0];
    h[i0 + 2] = pre + v[0] + v[1];
    h[i0 + 3] = pre + v[0] + v[1] + v[2];
    __syncthreads();
    for (int k = s + t; k < e; k += 256) {
        int key = binned[k];
        int p = atomicAdd(&h[key & 1023], 1);
        csr[s + p] = key >> 10;
    }
    __syncthreads();
#pragma unroll
    for (int j = 0; j < 4; ++j) {
        int node = nodeBase + i0 + j;
        if (node < N) cursor[node] = s + h[i0 + j];   // row end
    }
}

// ---------------- fallback degree histogram ----------------
__global__ void hist_kernel(const int* __restrict__ dst, int* __restrict__ degi, int E) {
    int e = blockIdx.x * blockDim.x + threadIdx.x;
    if (e < E) atomicAdd(&degi[dst[e]], 1);
}

// ------------- layer1 (fp16 rows): Ph = half(dinv * (emb[x] @ W1)), stride 32, pads=0 -------------
__global__ __launch_bounds__(256) void embed_gemm1_h(
        const int* __restrict__ x, const float* __restrict__ emb,
        const float* __restrict__ W1, const int* __restrict__ degi,
        __half* __restrict__ Ph, int N) {
    __shared__ float sW[D * D];
    for (int j = threadIdx.x; j < D * D; j += blockDim.x) sW[j] = W1[j];
    __syncthreads();
    int i = blockIdx.x * blockDim.x + threadIdx.x;
    if (i >= N) return;
    const float* er = emb + (size_t)x[i] * D;
    float t[D];
#pragma unroll
    for (int k = 0; k < D; ++k) t[k] = er[k];
    float dinv = rsqrtf((float)degi[i] + 1.0f);
    __half* row = Ph + (size_t)i * PH_STRIDE;
#pragma unroll
    for (int d = 0; d < D; ++d) {
        float acc = 0.0f;
#pragma unroll
        for (int k = 0; k < D; ++k) acc = fmaf(t[k], sW[k * D + d], acc);
        row[d] = __float2half(dinv * acc);
    }
#pragma unroll
    for (int d = D; d < PH_STRIDE; ++d) row[d] = __float2half(0.0f);
}

// ------- gather (half2): 32-lane group per node, 16 lanes x half2, 2 edges/step -------
__global__ __launch_bounds__(256) void gather_finish_h2(
        const int* __restrict__ csr, const int* __restrict__ cursor,
        const int* __restrict__ degi, const __half* __restrict__ Ph,
        const float* __restrict__ bias, float* __restrict__ Q, int N) {
    int idx = blockIdx.x * blockDim.x + threadIdx.x;
    int node = idx >> 5;
    if (node >= N) return;
    int lane = idx & 31;
    int sub = lane >> 4;       // 0 or 1 — which edge of the pair
    int f = lane & 15;         // half2 index within the 64B row
    int end = cursor[node];
    int dg = degi[node];
    int k = end - dg;
    const __half2* base = (const __half2*)Ph;   // row stride = 16 half2
    float ax = 0.0f, ay = 0.0f;
    if (sub == 0) {            // self loop
        float2 v = __half22float2(base[((size_t)node << 4) + f]);
        ax += v.x; ay += v.y;
    }
    while (k + 4 <= end) {
        int sA = csr[k + sub];
        int sB = csr[k + 2 + sub];
        float2 va = __half22float2(base[((size_t)sA << 4) + f]);
        float2 vb = __half22float2(base[((size_t)sB << 4) + f]);
        ax += va.x + vb.x;
        ay += va.y + vb.y;
        k += 4;
    }
    if (k + 2 <= end) {
        int sA = csr[k + sub];
        float2 va = __half22float2(base[((size_t)sA << 4) + f]);
        ax += va.x; ay += va.y;
        k += 2;
    }
    if (k < end && sub == 0) {
        int sA = csr[k];
        float2 va = __half22float2(base[((size_t)sA << 4) + f]);
        ax += va.x; ay += va.y;
    }
    ax += __shfl_down(ax, 16, 32);
    ay += __shfl_down(ay, 16, 32);
    if (sub == 0 && f < 13) {
        float dinv = rsqrtf((float)dg + 1.0f);
        int j0 = f << 1;
        Q[(size_t)node * D + j0] = fmaf(dinv, ax, bias[j0]);
        if (j0 + 1 < D) Q[(size_t)node * D + j0 + 1] = fmaf(dinv, ay, bias[j0 + 1]);
    }
}

// ------- layer2 (fp16 rows): t = relu(bn(Q)); Ph = half(dinv*(t@W2)), pads=0 -------
__global__ __launch_bounds__(256) void bn_gemm_h(
        const float* __restrict__ Qin,
        const float* __restrict__ mu, const float* __restrict__ rstd,
        const float* __restrict__ g, const float* __restrict__ be,
        const float* __restrict__ W, const int* __restrict__ degi,
        __half* __restrict__ Ph, int N) {
    __shared__ float sW[D * D];
    __shared__ float sScale[D], sShift[D];
    for (int j = threadIdx.x; j < D * D; j += blockDim.x) sW[j] = W[j];
    if (threadIdx.x < D) {
        float sc = rstd[threadIdx.x] * g[threadIdx.x];
        sScale[threadIdx.x] = sc;
        sShift[threadIdx.x] = be[threadIdx.x] - mu[threadIdx.x] * sc;
    }
    __syncthreads();
    int i = blockIdx.x * blockDim.x + threadIdx.x;
    if (i >= N) return;
    float t[D];
#pragma unroll
    for (int d = 0; d < D; ++d)
        t[d] = fmaxf(0.0f, fmaf(Qin[i * D + d], sScale[d], sShift[d]));
    float dinv = rsqrtf((float)degi[i] + 1.0f);
    __half* row = Ph + (size_t)i * PH_STRIDE;
#pragma unroll
    for (int d = 0; d < D; ++d) {
        float acc = 0.0f;
#pragma unroll
        for (int k = 0; k < D; ++k) acc = fmaf(t[k], sW[k * D + d], acc);
        row[d] = __float2half(dinv * acc);
    }
#pragma unroll
    for (int d = D; d < PH_STRIDE; ++d) row[d] = __float2half(0.0f);
}

// ---------------- fp32 fallback kernels (atomic-scatter path) ----------------
__global__ __launch_bounds__(256) void embed_gemm1(
        const int* __restrict__ x, const float* __restrict__ emb,
        const float* __restrict__ W1, const int* __restrict__ degi,
        float* __restrict__ P, float* __restrict__ Qdup, int N) {
    __shared__ float sW[D * D];
    for (int j = threadIdx.x; j < D * D; j += blockDim.x) sW[j] = W1[j];
    __syncthreads();
    int i = blockIdx.x * blockDim.x + threadIdx.x;
    if (i >= N) return;
    const float* er = emb + (size_t)x[i] * D;
    float t[D];
#pragma unroll
    for (int k = 0; k < D; ++k) t[k] = er[k];
    float dinv = rsqrtf((float)degi[i] + 1.0f);
#pragma unroll
    for (int d = 0; d < D; ++d) {
        float acc = 0.0f;
#pragma unroll
        for (int k = 0; k < D; ++k) acc = fmaf(t[k], sW[k * D + d], acc);
        float v = dinv * acc;
        P[i * D + d] = v;
        if (Qdup) Qdup[i * D + d] = v;
    }
}

__global__ void scatter_kernel(const int* __restrict__ src, const int* __restrict__ dst,
                               const float* __restrict__ A, float* __restrict__ B, int E) {
    int idx = blockIdx.x * blockDim.x + threadIdx.x;
    int e = idx >> 5;
    int lane = idx & 31;
    if (e >= E || lane >= D) return;
    atomicAdd(&B[dst[e] * D + lane], A[src[e] * D + lane]);
}

__global__ __launch_bounds__(256) void transform_kernel(
        float* __restrict__ Q, const int* __restrict__ degi,
        const float* __restrict__ bias, int N) {
    int i = blockIdx.x * blockDim.x + threadIdx.x;
    if (i >= N) return;
    float dinv = rsqrtf((float)degi[i] + 1.0f);
#pragma unroll
    for (int d = 0; d < D; ++d)
        Q[i * D + d] = fmaf(dinv, Q[i * D + d], bias[d]);
}

__global__ __launch_bounds__(256) void bn_gemm(
        const float* __restrict__ Qin,
        const float* __restrict__ mu, const float* __restrict__ rstd,
        const float* __restrict__ g, const float* __restrict__ be,
        const float* __restrict__ W, const int* __restrict__ degi,
        float* __restrict__ P, float* __restrict__ Qdup, int N) {
    __shared__ float sW[D * D];
    __shared__ float sScale[D], sShift[D];
    for (int j = threadIdx.x; j < D * D; j += blockDim.x) sW[j] = W[j];
    if (threadIdx.x < D) {
        float sc = rstd[threadIdx.x] * g[threadIdx.x];
        sScale[threadIdx.x] = sc;
        sShift[threadIdx.x] = be[threadIdx.x] - mu[threadIdx.x] * sc;
    }
    __syncthreads();
    int i = blockIdx.x * blockDim.x + threadIdx.x;
    if (i >= N) return;
    float t[D];
#pragma unroll
    for (int d = 0; d < D; ++d)
        t[d] = fmaxf(0.0f, fmaf(Qin[i * D + d], sScale[d], sShift[d]));
    float dinv = rsqrtf((float)degi[i] + 1.0f);
#pragma unroll
    for (int d = 0; d < D; ++d) {
        float acc = 0.0f;
#pragma unroll
        for (int k = 0; k < D; ++k) acc = fmaf(t[k], sW[k * D + d], acc);
        float v = dinv * acc;
        P[i * D + d] = v;
        if (Qdup) Qdup[i * D + d] = v;
    }
}

// ---------------- stats over Q: st[0..24]=sum, st[25..49]=sumsq ----------------
__global__ __launch_bounds__(256) void stats_kernel(
        const float* __restrict__ Q, float* __restrict__ st, int N) {
    float ls[D], lq[D];
#pragma unroll
    for (int d = 0; d < D; ++d) { ls[d] = 0.0f; lq[d] = 0.0f; }
    for (int i = blockIdx.x * blockDim.x + threadIdx.x; i < N;
         i += gridDim.x * blockDim.x) {
#pragma unroll
        for (int d = 0; d < D; ++d) {
            float v = Q[i * D + d];
            ls[d] += v;
            lq[d] += v * v;
        }
    }
#pragma unroll
    for (int d = 0; d < D; ++d) {
        for (int off = 32; off > 0; off >>= 1) {
            ls[d] += __shfl_down(ls[d], off, 64);
            lq[d] += __shfl_down(lq[d], off, 64);
        }
    }
    __shared__ float red[4][2 * D];
    int wave = threadIdx.x >> 6;
    int lane = threadIdx.x & 63;
    if (lane == 0) {
#pragma unroll
        for (int d = 0; d < D; ++d) {
            red[wave][d] = ls[d];
            red[wave][D + d] = lq[d];
        }
    }
    __syncthreads();
    if (threadIdx.x < 2 * D) {
        float t = red[0][threadIdx.x] + red[1][threadIdx.x] +
                  red[2][threadIdx.x] + red[3][threadIdx.x];
        atomicAdd(&st[threadIdx.x], t);
    }
}

// ---------------- mu / rstd ----------------
__global__ void musig_kernel(const float* __restrict__ sum, const float* __restrict__ sq,
                             float* __restrict__ mu, float* __restrict__ rstd, float invN) {
    int d = threadIdx.x;
    if (d < D) {
        float m = sum[d] * invN;
        float v = fmaxf(sq[d] * invN - m * m, 0.0f);
        mu[d] = m;
        rstd[d] = rsqrtf(v + 1e-5f);
    }
}

// ------- head: t = relu(bn(Q)); m = relu(t@Wm1+bm1); out = sigmoid(m@Wm2+bm2) -------
__global__ __launch_bounds__(256) void final_kernel(
        const float* __restrict__ Q,
        const float* __restrict__ mu, const float* __restrict__ rstd,
        const float* __restrict__ g, const float* __restrict__ be,
        const float* __restrict__ Wm1, const float* __restrict__ bm1,
        const float* __restrict__ Wm2, const float* __restrict__ bm2,
        float* __restrict__ out, int N) {
    __shared__ float sW1[D * 12];
    __shared__ float sb1[12], sW2[12];
    __shared__ float sScale[D], sShift[D];
    __shared__ float sb2;
    for (int j = threadIdx.x; j < D * 12; j += blockDim.x) sW1[j] = Wm1[j];
    if (threadIdx.x < 12) {
        sb1[threadIdx.x] = bm1[threadIdx.x];
        sW2[threadIdx.x] = Wm2[threadIdx.x];
    }
    if (threadIdx.x < D) {
        float sc = rstd[threadIdx.x] * g[threadIdx.x];
        sScale[threadIdx.x] = sc;
        sShift[threadIdx.x] = be[threadIdx.x] - mu[threadIdx.x] * sc;
    }
    if (threadIdx.x == 0) sb2 = bm2[0];
    __syncthreads();
    int i = blockIdx.x * blockDim.x + threadIdx.x;
    if (i >= N) return;
    float t[D];
#pragma unroll
    for (int d = 0; d < D; ++d)
        t[d] = fmaxf(0.0f, fmaf(Q[i * D + d], sScale[d], sShift[d]));
    float z = sb2;
#pragma unroll
    for (int j = 0; j < 12; ++j) {
        float m = sb1[j];
#pragma unroll
        for (int k = 0; k < D; ++k) m = fmaf(t[k], sW1[k * 12 + j], m);
        m = fmaxf(0.0f, m);
        z = fmaf(m, sW2[j], z);
    }
    out[i] = 1.0f / (1.0f + expf(-z));
}

extern "C" void kernel_launch(void* const* d_in, const int* in_sizes, int n_in,
                              void* d_out, int out_size, void* d_ws, size_t ws_size,
                              hipStream_t stream) {
    const int*   x    = (const int*)d_in[0];
    const int*   ei   = (const int*)d_in[1];
    const float* emb  = (const float*)d_in[2];
    const float* W1   = (const float*)d_in[3];
    const float* b1   = (const float*)d_in[4];
    const float* g1   = (const float*)d_in[5];
    const float* be1  = (const float*)d_in[6];
    const float* W2   = (const float*)d_in[7];
    const float* b2   = (const float*)d_in[8];
    const float* g2   = (const float*)d_in[9];
    const float* be2  = (const float*)d_in[10];
    const float* Wm1  = (const float*)d_in[11];
    const float* bm1  = (const float*)d_in[12];
    const float* Wm2  = (const float*)d_in[13];
    const float* bm2  = (const float*)d_in[14];
    float* out = (float*)d_out;

    int N = in_sizes[0];
    int E = in_sizes[1] / 2;
    const int* src = ei;
    const int* dst = ei + E;

    int nbBin = (E + BIN_EDGES - 1) / BIN_EDGES;
    // words: degi N + cursor N + csr E + bCount/bBase 512 + hist2D nbBin*256 + Ph 16N + Q 25N + stats 200
    size_t csrNeed = ((size_t)43 * N + E + 512 + (size_t)nbBin * NBK + 200) * 4;
    bool useCSR = (ws_size >= csrNeed) && (N <= NBK * 1024) && (nbBin <= 512) &&
                  ((size_t)E <= (size_t)N * D);

    int nbN  = (N + 255) / 256;
    int nbE  = (E + 255) / 256;
    int nbG  = (int)(((long)N * 32 + 255) / 256);
    int nbS  = (int)(((long)E * 32 + 255) / 256);

    if (useCSR) {
        int*    degi    = (int*)d_ws;                   // N
        int*    cursor  = degi + N;                     // N
        int*    csr     = cursor + N;                   // E
        int*    bCount  = csr + E;                      // 256
        int*    bBase   = bCount + NBK;                 // 256
        int*    hist2D  = bBase + NBK;                  // nbBin*256
        __half* Ph      = (__half*)(hist2D + (size_t)nbBin * NBK);   // N*32 halves
        float*  Q       = (float*)(Ph + (size_t)N * PH_STRIDE);      // N*25
        float*  stats   = Q + (size_t)N * D;            // 200
        int*    binned  = (int*)Q;                      // E ints (aliases Q; dead before Q written)
        float* st1 = stats;       float* st2 = stats + 50;
        float* mu1 = stats + 100; float* rs1 = stats + 125;
        float* mu2 = stats + 150; float* rs2 = stats + 175;

        hipMemsetAsync(stats, 0, 100 * sizeof(float), stream);

        int nbBkt = (N + 1023) / 1024;

        binA<<<nbBin, 256, 0, stream>>>(dst, hist2D, E);
        colscan<<<NBK, 512, 0, stream>>>(hist2D, bCount, nbBin);
        bucket_scan<<<1, NBK, 0, stream>>>(bCount, bBase);
        binB<<<nbBin, 256, 0, stream>>>(src, dst, hist2D, bBase, binned, E);
        bucket_fill<<<nbBkt, 256, 0, stream>>>(binned, bBase, bCount, degi, cursor, csr, N);
        embed_gemm1_h<<<nbN, 256, 0, stream>>>(x, emb, W1, degi, Ph, N);
        gather_finish_h2<<<nbG, 256, 0, stream>>>(csr, cursor, degi, Ph, b1, Q, N);
        stats_kernel<<<STATS_BLOCKS, 256, 0, stream>>>(Q, st1, N);
        musig_kernel<<<1, 64, 0, stream>>>(st1, st1 + 25, mu1, rs1, 1.0f / (float)N);
        bn_gemm_h<<<nbN, 256, 0, stream>>>(Q, mu1, rs1, g1, be1, W2, degi, Ph, N);
        gather_finish_h2<<<nbG, 256, 0, stream>>>(csr, cursor, degi, Ph, b2, Q, N);
        stats_kernel<<<STATS_BLOCKS, 256, 0, stream>>>(Q, st2, N);
        musig_kernel<<<1, 64, 0, stream>>>(st2, st2 + 25, mu2, rs2, 1.0f / (float)N);
        final_kernel<<<nbN, 256, 0, stream>>>(Q, mu2, rs2, g2, be2, Wm1, bm1, Wm2, bm2, out, N);
    } else {
        // fallback: fp32 atomic-scatter path
        int*   degi  = (int*)d_ws;                  // N
        float* P     = (float*)(degi + N);          // N*D
        float* Q     = P + (size_t)N * D;           // N*D
        float* stats = Q + (size_t)N * D;           // 200
        float* st1 = stats;       float* st2 = stats + 50;
        float* mu1 = stats + 100; float* rs1 = stats + 125;
        float* mu2 = stats + 150; float* rs2 = stats + 175;

        hipMemsetAsync(degi, 0, (size_t)N * sizeof(int), stream);
        hipMemsetAsync(stats, 0, 100 * sizeof(float), stream);

        hist_kernel<<<nbE, 256, 0, stream>>>(dst, degi, E);
        embed_gemm1<<<nbN, 256, 0, stream>>>(x, emb, W1, degi, P, Q, N);
        scatter_kernel<<<nbS, 256, 0, stream>>>(src, dst, P, Q, E);
        transform_kernel<<<nbN, 256, 0, stream>>>(Q, degi, b1, N);
        stats_kernel<<<STATS_BLOCKS, 256, 0, stream>>>(Q, st1, N);
        musig_kernel<<<1, 64, 0, stream>>>(st1, st1 + 25, mu1, rs1, 1.0f / (float)N);
        bn_gemm<<<nbN, 256, 0, stream>>>(Q, mu1, rs1, g1, be1, W2, degi, P, Q, N);
        scatter_kernel<<<nbS, 256, 0, stream>>>(src, dst, P, Q, E);
        transform_kernel<<<nbN, 256, 0, stream>>>(Q, degi, b2, N);
        stats_kernel<<<STATS_BLOCKS, 256, 0, stream>>>(Q, st2, N);
        musig_kernel<<<1, 64, 0, stream>>>(st2, st2 + 25, mu2, rs2, 1.0f / (float)N);
        final_kernel<<<nbN, 256, 0, stream>>>(Q, mu2, rs2, g2, be2, Wm1, bm1, Wm2, bm2, out, N);
    }
}

// Round 7
// 376.562 us; speedup vs baseline: 7.6231x; 1.1086x over previous
//
#include <hip/hip_runtime.h>
#include <hip/hip_fp16.h>
#include <math.h>

#define D 25
#define PH_STRIDE 32    // fp16 row padded to 32 elems = 64 B = one cache line
#define STATS_BLOCKS 512
#define NBK 256         // buckets of 1024 nodes
#define BIN_EDGES 8192  // edges per bin block (256 thr x 32)
#define EPS 1e-5f

// ---------------- binA: per-(block,bucket) histogram, no global atomics ----------------
__global__ __launch_bounds__(256) void binA(const int* __restrict__ dst,
                                            int* __restrict__ hist2D, int E) {
    __shared__ int h[NBK];
    h[threadIdx.x] = 0;
    __syncthreads();
    int base = blockIdx.x * BIN_EDGES;
#pragma unroll
    for (int j = 0; j < 32; ++j) {
        int idx = base + j * 256 + threadIdx.x;
        if (idx < E) atomicAdd(&h[dst[idx] >> 10], 1);
    }
    __syncthreads();
    hist2D[blockIdx.x * NBK + threadIdx.x] = h[threadIdx.x];
}

// ------- colscan: per bucket, exclusive scan over blocks (in place) + total -------
__global__ __launch_bounds__(512) void colscan(int* __restrict__ hist2D,
                                               int* __restrict__ bCount, int nbBin) {
    __shared__ int s[512];
    int b = blockIdx.x;
    int j = threadIdx.x;
    int v = (j < nbBin) ? hist2D[j * NBK + b] : 0;
    s[j] = v;
    __syncthreads();
    for (int off = 1; off < 512; off <<= 1) {
        int x = (j >= off) ? s[j - off] : 0;
        __syncthreads();
        s[j] += x;
        __syncthreads();
    }
    if (j < nbBin) hist2D[j * NBK + b] = s[j] - v;   // exclusive prefix
    if (j == 0) bCount[b] = s[511];
}

// ---------------- exclusive scan of bucket totals ----------------
__global__ void bucket_scan(const int* __restrict__ bCount, int* __restrict__ bBase) {
    __shared__ int s[NBK];
    int t = threadIdx.x;
    s[t] = bCount[t];
    __syncthreads();
    for (int off = 1; off < NBK; off <<= 1) {
        int x = (t >= off) ? s[t - off] : 0;
        __syncthreads();
        s[t] += x;
        __syncthreads();
    }
    bBase[t] = (t > 0) ? s[t - 1] : 0;
}

// ------- binB: write keys grouped by bucket using precomputed bases + LDS rank -------
__global__ __launch_bounds__(256) void binB(const int* __restrict__ src,
                                            const int* __restrict__ dst,
                                            const int* __restrict__ hist2D,
                                            const int* __restrict__ bBase,
                                            int* __restrict__ binned, int E) {
    __shared__ int rank[NBK], basew[NBK];
    int t = threadIdx.x;
    rank[t] = 0;
    basew[t] = bBase[t] + hist2D[blockIdx.x * NBK + t];
    __syncthreads();
    int base = blockIdx.x * BIN_EDGES;
#pragma unroll
    for (int j = 0; j < 32; ++j) {
        int idx = base + j * 256 + t;
        if (idx < E) {
            int d = dst[idx];
            int b = d >> 10;
            int r = atomicAdd(&rank[b], 1);
            binned[basew[b] + r] = (src[idx] << 10) | (d & 1023);
        }
    }
}

// ------- per-bucket CSR fill: block b owns nodes [b*1024,(b+1)*1024) -------
__global__ __launch_bounds__(256) void bucket_fill(const int* __restrict__ binned,
                                                   const int* __restrict__ bucketBase,
                                                   const int* __restrict__ bucketCount,
                                                   int* __restrict__ degi, int* __restrict__ cursor,
                                                   int* __restrict__ csr, int N) {
    int b = blockIdx.x;
    int nodeBase = b << 10;
    if (nodeBase >= N) return;
    int s = bucketBase[b];
    int e = s + bucketCount[b];
    __shared__ int h[1024];
    __shared__ int s2[256];
    int t = threadIdx.x;
    int i0 = t * 4;
#pragma unroll
    for (int j = 0; j < 4; ++j) h[i0 + j] = 0;
    __syncthreads();
    for (int k = s + t; k < e; k += 256)
        atomicAdd(&h[binned[k] & 1023], 1);
    __syncthreads();
    int v[4];
#pragma unroll
    for (int j = 0; j < 4; ++j) {
        v[j] = h[i0 + j];
        int node = nodeBase + i0 + j;
        if (node < N) degi[node] = v[j];
    }
    s2[t] = v[0] + v[1] + v[2] + v[3];
    __syncthreads();
    for (int off = 1; off < 256; off <<= 1) {
        int x = (t >= off) ? s2[t - off] : 0;
        __syncthreads();
        s2[t] += x;
        __syncthreads();
    }
    int pre = (t > 0) ? s2[t - 1] : 0;
    h[i0]     = pre;
    h[i0 + 1] = pre + v[0];
    h[i0 + 2] = pre + v[0] + v[1];
    h[i0 + 3] = pre + v[0] + v[1] + v[2];
    __syncthreads();
    for (int k = s + t; k < e; k += 256) {
        int key = binned[k];
        int p = atomicAdd(&h[key & 1023], 1);
        csr[s + p] = key >> 10;
    }
    __syncthreads();
#pragma unroll
    for (int j = 0; j < 4; ++j) {
        int node = nodeBase + i0 + j;
        if (node < N) cursor[node] = s + h[i0 + j];   // row end
    }
}

// ---------------- fallback degree histogram ----------------
__global__ void hist_kernel(const int* __restrict__ dst, int* __restrict__ degi, int E) {
    int e = blockIdx.x * blockDim.x + threadIdx.x;
    if (e < E) atomicAdd(&degi[dst[e]], 1);
}

// ------------- layer1 (fp16 rows): Ph = half(dinv * (emb[x] @ W1)), stride 32, pads=0 -------------
__global__ __launch_bounds__(256) void embed_gemm1_h(
        const int* __restrict__ x, const float* __restrict__ emb,
        const float* __restrict__ W1, const int* __restrict__ degi,
        __half* __restrict__ Ph, int N) {
    __shared__ float sW[D * D];
    for (int j = threadIdx.x; j < D * D; j += blockDim.x) sW[j] = W1[j];
    __syncthreads();
    int i = blockIdx.x * blockDim.x + threadIdx.x;
    if (i >= N) return;
    const float* er = emb + (size_t)x[i] * D;
    float t[D];
#pragma unroll
    for (int k = 0; k < D; ++k) t[k] = er[k];
    float dinv = rsqrtf((float)degi[i] + 1.0f);
    __half* row = Ph + (size_t)i * PH_STRIDE;
#pragma unroll
    for (int d = 0; d < D; ++d) {
        float acc = 0.0f;
#pragma unroll
        for (int k = 0; k < D; ++k) acc = fmaf(t[k], sW[k * D + d], acc);
        row[d] = __float2half(dinv * acc);
    }
#pragma unroll
    for (int d = D; d < PH_STRIDE; ++d) row[d] = __float2half(0.0f);
}

// ------- gather: 16-lane walk per node, 4 nodes per wave, 4 edges in flight per walk -------
__global__ __launch_bounds__(256) void gather_finish_w4(
        const int* __restrict__ csr, const int* __restrict__ cursor,
        const int* __restrict__ degi, const __half* __restrict__ Ph,
        const float* __restrict__ bias, float* __restrict__ Q, int N) {
    int node = blockIdx.x * 16 + (threadIdx.x >> 4);
    if (node >= N) return;
    int f = threadIdx.x & 15;                 // half2 index within the 64B row
    int end = cursor[node];
    int dg = degi[node];
    int k = end - dg;
    const __half2* rowb = (const __half2*)Ph; // row stride = 16 half2
    float2 sv = __half22float2(rowb[((size_t)node << 4) + f]);  // self loop
    float ax = sv.x, ay = sv.y;
    for (; k + 4 <= end; k += 4) {
        int s0 = csr[k], s1 = csr[k + 1], s2 = csr[k + 2], s3 = csr[k + 3];
        float2 v0 = __half22float2(rowb[((size_t)s0 << 4) + f]);
        float2 v1 = __half22float2(rowb[((size_t)s1 << 4) + f]);
        float2 v2 = __half22float2(rowb[((size_t)s2 << 4) + f]);
        float2 v3 = __half22float2(rowb[((size_t)s3 << 4) + f]);
        ax += (v0.x + v1.x) + (v2.x + v3.x);
        ay += (v0.y + v1.y) + (v2.y + v3.y);
    }
    for (; k < end; ++k) {
        float2 v = __half22float2(rowb[((size_t)csr[k] << 4) + f]);
        ax += v.x; ay += v.y;
    }
    if (f < 13) {
        float dinv = rsqrtf((float)dg + 1.0f);
        int j0 = f << 1;
        Q[(size_t)node * D + j0] = fmaf(dinv, ax, bias[j0]);
        if (f < 12) Q[(size_t)node * D + j0 + 1] = fmaf(dinv, ay, bias[j0 + 1]);
    }
}

// ------- layer2 (fp16 rows): mu/rstd inline from st; t = relu(bn(Q)); Ph = half(dinv*(t@W2)) -------
__global__ __launch_bounds__(256) void bn_gemm_h(
        const float* __restrict__ Qin, const float* __restrict__ st, float invN,
        const float* __restrict__ g, const float* __restrict__ be,
        const float* __restrict__ W, const int* __restrict__ degi,
        __half* __restrict__ Ph, int N) {
    __shared__ float sW[D * D];
    __shared__ float sScale[D], sShift[D];
    for (int j = threadIdx.x; j < D * D; j += blockDim.x) sW[j] = W[j];
    if (threadIdx.x < D) {
        float m = st[threadIdx.x] * invN;
        float v = fmaxf(st[D + threadIdx.x] * invN - m * m, 0.0f);
        float sc = rsqrtf(v + EPS) * g[threadIdx.x];
        sScale[threadIdx.x] = sc;
        sShift[threadIdx.x] = be[threadIdx.x] - m * sc;
    }
    __syncthreads();
    int i = blockIdx.x * blockDim.x + threadIdx.x;
    if (i >= N) return;
    float t[D];
#pragma unroll
    for (int d = 0; d < D; ++d)
        t[d] = fmaxf(0.0f, fmaf(Qin[i * D + d], sScale[d], sShift[d]));
    float dinv = rsqrtf((float)degi[i] + 1.0f);
    __half* row = Ph + (size_t)i * PH_STRIDE;
#pragma unroll
    for (int d = 0; d < D; ++d) {
        float acc = 0.0f;
#pragma unroll
        for (int k = 0; k < D; ++k) acc = fmaf(t[k], sW[k * D + d], acc);
        row[d] = __float2half(dinv * acc);
    }
#pragma unroll
    for (int d = D; d < PH_STRIDE; ++d) row[d] = __float2half(0.0f);
}

// ---------------- fp32 fallback kernels (atomic-scatter path) ----------------
__global__ __launch_bounds__(256) void embed_gemm1(
        const int* __restrict__ x, const float* __restrict__ emb,
        const float* __restrict__ W1, const int* __restrict__ degi,
        float* __restrict__ P, float* __restrict__ Qdup, int N) {
    __shared__ float sW[D * D];
    for (int j = threadIdx.x; j < D * D; j += blockDim.x) sW[j] = W1[j];
    __syncthreads();
    int i = blockIdx.x * blockDim.x + threadIdx.x;
    if (i >= N) return;
    const float* er = emb + (size_t)x[i] * D;
    float t[D];
#pragma unroll
    for (int k = 0; k < D; ++k) t[k] = er[k];
    float dinv = rsqrtf((float)degi[i] + 1.0f);
#pragma unroll
    for (int d = 0; d < D; ++d) {
        float acc = 0.0f;
#pragma unroll
        for (int k = 0; k < D; ++k) acc = fmaf(t[k], sW[k * D + d], acc);
        float v = dinv * acc;
        P[i * D + d] = v;
        if (Qdup) Qdup[i * D + d] = v;
    }
}

__global__ void scatter_kernel(const int* __restrict__ src, const int* __restrict__ dst,
                               const float* __restrict__ A, float* __restrict__ B, int E) {
    int idx = blockIdx.x * blockDim.x + threadIdx.x;
    int e = idx >> 5;
    int lane = idx & 31;
    if (e >= E || lane >= D) return;
    atomicAdd(&B[dst[e] * D + lane], A[src[e] * D + lane]);
}

__global__ __launch_bounds__(256) void transform_kernel(
        float* __restrict__ Q, const int* __restrict__ degi,
        const float* __restrict__ bias, int N) {
    int i = blockIdx.x * blockDim.x + threadIdx.x;
    if (i >= N) return;
    float dinv = rsqrtf((float)degi[i] + 1.0f);
#pragma unroll
    for (int d = 0; d < D; ++d)
        Q[i * D + d] = fmaf(dinv, Q[i * D + d], bias[d]);
}

__global__ __launch_bounds__(256) void bn_gemm(
        const float* __restrict__ Qin, const float* __restrict__ st, float invN,
        const float* __restrict__ g, const float* __restrict__ be,
        const float* __restrict__ W, const int* __restrict__ degi,
        float* __restrict__ P, float* __restrict__ Qdup, int N) {
    __shared__ float sW[D * D];
    __shared__ float sScale[D], sShift[D];
    for (int j = threadIdx.x; j < D * D; j += blockDim.x) sW[j] = W[j];
    if (threadIdx.x < D) {
        float m = st[threadIdx.x] * invN;
        float v = fmaxf(st[D + threadIdx.x] * invN - m * m, 0.0f);
        float sc = rsqrtf(v + EPS) * g[threadIdx.x];
        sScale[threadIdx.x] = sc;
        sShift[threadIdx.x] = be[threadIdx.x] - m * sc;
    }
    __syncthreads();
    int i = blockIdx.x * blockDim.x + threadIdx.x;
    if (i >= N) return;
    float t[D];
#pragma unroll
    for (int d = 0; d < D; ++d)
        t[d] = fmaxf(0.0f, fmaf(Qin[i * D + d], sScale[d], sShift[d]));
    float dinv = rsqrtf((float)degi[i] + 1.0f);
#pragma unroll
    for (int d = 0; d < D; ++d) {
        float acc = 0.0f;
#pragma unroll
        for (int k = 0; k < D; ++k) acc = fmaf(t[k], sW[k * D + d], acc);
        float v = dinv * acc;
        P[i * D + d] = v;
        if (Qdup) Qdup[i * D + d] = v;
    }
}

// ---------------- stats over Q: st[0..24]=sum, st[25..49]=sumsq ----------------
__global__ __launch_bounds__(256) void stats_kernel(
        const float* __restrict__ Q, float* __restrict__ st, int N) {
    float ls[D], lq[D];
#pragma unroll
    for (int d = 0; d < D; ++d) { ls[d] = 0.0f; lq[d] = 0.0f; }
    for (int i = blockIdx.x * blockDim.x + threadIdx.x; i < N;
         i += gridDim.x * blockDim.x) {
#pragma unroll
        for (int d = 0; d < D; ++d) {
            float v = Q[i * D + d];
            ls[d] += v;
            lq[d] += v * v;
        }
    }
#pragma unroll
    for (int d = 0; d < D; ++d) {
        for (int off = 32; off > 0; off >>= 1) {
            ls[d] += __shfl_down(ls[d], off, 64);
            lq[d] += __shfl_down(lq[d], off, 64);
        }
    }
    __shared__ float red[4][2 * D];
    int wave = threadIdx.x >> 6;
    int lane = threadIdx.x & 63;
    if (lane == 0) {
#pragma unroll
        for (int d = 0; d < D; ++d) {
            red[wave][d] = ls[d];
            red[wave][D + d] = lq[d];
        }
    }
    __syncthreads();
    if (threadIdx.x < 2 * D) {
        float t = red[0][threadIdx.x] + red[1][threadIdx.x] +
                  red[2][threadIdx.x] + red[3][threadIdx.x];
        atomicAdd(&st[threadIdx.x], t);
    }
}

// ------- head: mu/rstd inline from st; t = relu(bn(Q)); m = relu(t@Wm1+bm1); out = sigmoid -------
__global__ __launch_bounds__(256) void final_kernel(
        const float* __restrict__ Q, const float* __restrict__ st, float invN,
        const float* __restrict__ g, const float* __restrict__ be,
        const float* __restrict__ Wm1, const float* __restrict__ bm1,
        const float* __restrict__ Wm2, const float* __restrict__ bm2,
        float* __restrict__ out, int N) {
    __shared__ float sW1[D * 12];
    __shared__ float sb1[12], sW2[12];
    __shared__ float sScale[D], sShift[D];
    __shared__ float sb2;
    for (int j = threadIdx.x; j < D * 12; j += blockDim.x) sW1[j] = Wm1[j];
    if (threadIdx.x < 12) {
        sb1[threadIdx.x] = bm1[threadIdx.x];
        sW2[threadIdx.x] = Wm2[threadIdx.x];
    }
    if (threadIdx.x < D) {
        float m = st[threadIdx.x] * invN;
        float v = fmaxf(st[D + threadIdx.x] * invN - m * m, 0.0f);
        float sc = rsqrtf(v + EPS) * g[threadIdx.x];
        sScale[threadIdx.x] = sc;
        sShift[threadIdx.x] = be[threadIdx.x] - m * sc;
    }
    if (threadIdx.x == 0) sb2 = bm2[0];
    __syncthreads();
    int i = blockIdx.x * blockDim.x + threadIdx.x;
    if (i >= N) return;
    float t[D];
#pragma unroll
    for (int d = 0; d < D; ++d)
        t[d] = fmaxf(0.0f, fmaf(Q[i * D + d], sScale[d], sShift[d]));
    float z = sb2;
#pragma unroll
    for (int j = 0; j < 12; ++j) {
        float m = sb1[j];
#pragma unroll
        for (int k = 0; k < D; ++k) m = fmaf(t[k], sW1[k * 12 + j], m);
        m = fmaxf(0.0f, m);
        z = fmaf(m, sW2[j], z);
    }
    out[i] = 1.0f / (1.0f + expf(-z));
}

extern "C" void kernel_launch(void* const* d_in, const int* in_sizes, int n_in,
                              void* d_out, int out_size, void* d_ws, size_t ws_size,
                              hipStream_t stream) {
    const int*   x    = (const int*)d_in[0];
    const int*   ei   = (const int*)d_in[1];
    const float* emb  = (const float*)d_in[2];
    const float* W1   = (const float*)d_in[3];
    const float* b1   = (const float*)d_in[4];
    const float* g1   = (const float*)d_in[5];
    const float* be1  = (const float*)d_in[6];
    const float* W2   = (const float*)d_in[7];
    const float* b2   = (const float*)d_in[8];
    const float* g2   = (const float*)d_in[9];
    const float* be2  = (const float*)d_in[10];
    const float* Wm1  = (const float*)d_in[11];
    const float* bm1  = (const float*)d_in[12];
    const float* Wm2  = (const float*)d_in[13];
    const float* bm2  = (const float*)d_in[14];
    float* out = (float*)d_out;

    int N = in_sizes[0];
    int E = in_sizes[1] / 2;
    const int* src = ei;
    const int* dst = ei + E;
    float invN = 1.0f / (float)N;

    int nbBin = (E + BIN_EDGES - 1) / BIN_EDGES;
    size_t csrNeed = ((size_t)43 * N + E + 512 + (size_t)nbBin * NBK + 200) * 4;
    bool useCSR = (ws_size >= csrNeed) && (N <= NBK * 1024) && (nbBin <= 512) &&
                  ((size_t)E <= (size_t)N * D);

    int nbN  = (N + 255) / 256;
    int nbE  = (E + 255) / 256;
    int nbG  = (N + 15) / 16;            // 16 nodes per 256-thread block
    int nbS  = (int)(((long)E * 32 + 255) / 256);

    if (useCSR) {
        int*    degi    = (int*)d_ws;                   // N
        int*    cursor  = degi + N;                     // N
        int*    csr     = cursor + N;                   // E
        int*    bCount  = csr + E;                      // 256
        int*    bBase   = bCount + NBK;                 // 256
        int*    hist2D  = bBase + NBK;                  // nbBin*256
        __half* Ph      = (__half*)(hist2D + (size_t)nbBin * NBK);   // N*32 halves
        float*  Q       = (float*)(Ph + (size_t)N * PH_STRIDE);      // N*25
        float*  stats   = Q + (size_t)N * D;            // 100
        int*    binned  = (int*)Q;                      // E ints (aliases Q; dead before Q written)
        float* st1 = stats;
        float* st2 = stats + 50;

        hipMemsetAsync(stats, 0, 100 * sizeof(float), stream);

        int nbBkt = (N + 1023) / 1024;

        binA<<<nbBin, 256, 0, stream>>>(dst, hist2D, E);
        colscan<<<NBK, 512, 0, stream>>>(hist2D, bCount, nbBin);
        bucket_scan<<<1, NBK, 0, stream>>>(bCount, bBase);
        binB<<<nbBin, 256, 0, stream>>>(src, dst, hist2D, bBase, binned, E);
        bucket_fill<<<nbBkt, 256, 0, stream>>>(binned, bBase, bCount, degi, cursor, csr, N);
        embed_gemm1_h<<<nbN, 256, 0, stream>>>(x, emb, W1, degi, Ph, N);
        gather_finish_w4<<<nbG, 256, 0, stream>>>(csr, cursor, degi, Ph, b1, Q, N);
        stats_kernel<<<STATS_BLOCKS, 256, 0, stream>>>(Q, st1, N);
        bn_gemm_h<<<nbN, 256, 0, stream>>>(Q, st1, invN, g1, be1, W2, degi, Ph, N);
        gather_finish_w4<<<nbG, 256, 0, stream>>>(csr, cursor, degi, Ph, b2, Q, N);
        stats_kernel<<<STATS_BLOCKS, 256, 0, stream>>>(Q, st2, N);
        final_kernel<<<nbN, 256, 0, stream>>>(Q, st2, invN, g2, be2, Wm1, bm1, Wm2, bm2, out, N);
    } else {
        // fallback: fp32 atomic-scatter path
        int*   degi  = (int*)d_ws;                  // N
        float* P     = (float*)(degi + N);          // N*D
        float* Q     = P + (size_t)N * D;           // N*D
        float* stats = Q + (size_t)N * D;           // 100
        float* st1 = stats;
        float* st2 = stats + 50;

        hipMemsetAsync(degi, 0, (size_t)N * sizeof(int), stream);
        hipMemsetAsync(stats, 0, 100 * sizeof(float), stream);

        hist_kernel<<<nbE, 256, 0, stream>>>(dst, degi, E);
        embed_gemm1<<<nbN, 256, 0, stream>>>(x, emb, W1, degi, P, Q, N);
        scatter_kernel<<<nbS, 256, 0, stream>>>(src, dst, P, Q, E);
        transform_kernel<<<nbN, 256, 0, stream>>>(Q, degi, b1, N);
        stats_kernel<<<STATS_BLOCKS, 256, 0, stream>>>(Q, st1, N);
        bn_gemm<<<nbN, 256, 0, stream>>>(Q, st1, invN, g1, be1, W2, degi, P, Q, N);
        scatter_kernel<<<nbS, 256, 0, stream>>>(src, dst, P, Q, E);
        transform_kernel<<<nbN, 256, 0, stream>>>(Q, degi, b2, N);
        stats_kernel<<<STATS_BLOCKS, 256, 0, stream>>>(Q, st2, N);
        final_kernel<<<nbN, 256, 0, stream>>>(Q, st2, invN, g2, be2, Wm1, bm1, Wm2, bm2, out, N);
    }
}